// Round 3
// baseline (1689.303 us; speedup 1.0000x reference)
//
#include <hip/hip_runtime.h>
#include <hip/hip_bf16.h>

#define HW 16384   // 128*128

typedef unsigned short u16;
typedef unsigned int   u32;

__device__ __forceinline__ float b2f(u16 v) { return __uint_as_float((u32)v << 16); }
__device__ __forceinline__ u16 f2bf(float f) {
  u32 u = __float_as_uint(f);
  u32 r = (u + 0x7fffu + ((u >> 16) & 1u)) >> 16;
  return (u16)r;
}
__device__ __forceinline__ float bflo(u32 u) { return __uint_as_float(u << 16); }
__device__ __forceinline__ float bfhi(u32 u) { return __uint_as_float(u & 0xffff0000u); }
__device__ __forceinline__ u32 pk2(float a, float b) { return ((u32)f2bf(b) << 16) | (u32)f2bf(a); }

// ---------------------------------------------------------------------------
// K0: transpose w_dc (fp32) -> wT[(o*9+k)*128+ci]
// ---------------------------------------------------------------------------
__global__ __launch_bounds__(256) void k_init(const float* __restrict__ w_dc,
                                              float* __restrict__ wT) {
  int i2 = blockIdx.x * 256 + threadIdx.x;
  if (i2 < 147456) {
    int o = i2 / 1152, r = i2 % 1152;
    int k = r >> 7, ci = r & 127;
    wT[i2] = w_dc[(o * 128 + ci) * 9 + k];
  }
}

// ---------------------------------------------------------------------------
// K1: conv1 1x1 (K=256) + bn1a+relu + bn1b+relu -> out1 NHWC bf16 + NCHW bf16
// grid (2, 128, 4) = (o-half, h, b); block 256
// out1T lives in d_out (consumed by k_off before k_conv3 overwrites d_out).
// ---------------------------------------------------------------------------
__global__ __launch_bounds__(256) void k_conv1(const float* __restrict__ x,
                                               const float* __restrict__ w1,
                                               const float* __restrict__ s1a, const float* __restrict__ t1a,
                                               const float* __restrict__ s1b, const float* __restrict__ t1b,
                                               u16* __restrict__ out1,   // [b][h][w][o]
                                               u16* __restrict__ out1T)  // [b][o][h][w]
{
  __shared__ __align__(16) float wls[64 * 256];
  const int tid = threadIdx.x;
  const int ohalf = blockIdx.x, h = blockIdx.y, b = blockIdx.z;
  {
    const float4* w4 = (const float4*)(w1 + ohalf * 16384);
    float4* wl4 = (float4*)wls;
#pragma unroll
    for (int i = 0; i < 16; ++i) wl4[i * 256 + tid] = w4[i * 256 + tid];
  }
  __syncthreads();

  const int w0 = tid & 31, og = tid >> 5;   // 8 groups x 8 o
  float acc[8][4];
#pragma unroll
  for (int j = 0; j < 8; ++j)
#pragma unroll
    for (int q = 0; q < 4; ++q) acc[j][q] = 0.f;

  const float* xb = x + (size_t)b * 256 * HW + h * 128;
  for (int c4 = 0; c4 < 64; ++c4) {
    float xv[4][4];
#pragma unroll
    for (int cc = 0; cc < 4; ++cc)
#pragma unroll
      for (int q = 0; q < 4; ++q)
        xv[cc][q] = xb[(size_t)(c4 * 4 + cc) * HW + w0 + 32 * q];
#pragma unroll
    for (int j = 0; j < 8; ++j) {
      float4 wv = *(const float4*)&wls[(og * 8 + j) * 256 + c4 * 4];
#pragma unroll
      for (int q = 0; q < 4; ++q)
        acc[j][q] += wv.x * xv[0][q] + wv.y * xv[1][q] + wv.z * xv[2][q] + wv.w * xv[3][q];
    }
  }

  const int obase = ohalf * 64 + og * 8;
#pragma unroll
  for (int j = 0; j < 8; ++j) {
    int o = obase + j;
    float sa = s1a[o], ta = t1a[o];
    float sb = s1b[o], tb = t1b[o];
#pragma unroll
    for (int q = 0; q < 4; ++q) {
      float v = acc[j][q];
      v = fmaxf(sa * v + ta, 0.f);
      v = fmaxf(sb * v + tb, 0.f);
      acc[j][q] = v;
    }
  }
#pragma unroll
  for (int q = 0; q < 4; ++q) {
    int w = w0 + 32 * q;
    size_t pos = (size_t)((b * 128 + h) * 128 + w);
    uint4 pk;
    pk.x = pk2(acc[0][q], acc[1][q]);
    pk.y = pk2(acc[2][q], acc[3][q]);
    pk.z = pk2(acc[4][q], acc[5][q]);
    pk.w = pk2(acc[6][q], acc[7][q]);
    *(uint4*)&out1[pos * 128 + obase] = pk;
#pragma unroll
    for (int j = 0; j < 8; ++j)
      out1T[(size_t)(((b * 128 + obase + j) * 128 + h)) * 128 + w] = f2bf(acc[j][q]);
  }
}

// ---------------------------------------------------------------------------
// K2: downsample 1x1 (K=256): ident = sd*(conv + b_ds) + td  -> NCHW bf16
// ---------------------------------------------------------------------------
__global__ __launch_bounds__(256) void k_ident(const float* __restrict__ x,
                                               const float* __restrict__ w_ds,
                                               const float* __restrict__ b_ds,
                                               const float* __restrict__ sd, const float* __restrict__ td,
                                               u16* __restrict__ identb) {
  __shared__ __align__(16) float wls[64 * 256];
  const int tid = threadIdx.x;
  const int ohalf = blockIdx.x, h = blockIdx.y, b = blockIdx.z;
  {
    const float4* w4 = (const float4*)(w_ds + ohalf * 16384);
    float4* wl4 = (float4*)wls;
#pragma unroll
    for (int i = 0; i < 16; ++i) wl4[i * 256 + tid] = w4[i * 256 + tid];
  }
  __syncthreads();

  const int w0 = tid & 31, og = tid >> 5;
  float acc[8][4];
#pragma unroll
  for (int j = 0; j < 8; ++j)
#pragma unroll
    for (int q = 0; q < 4; ++q) acc[j][q] = 0.f;

  const float* xb = x + (size_t)b * 256 * HW + h * 128;
  for (int c4 = 0; c4 < 64; ++c4) {
    float xv[4][4];
#pragma unroll
    for (int cc = 0; cc < 4; ++cc)
#pragma unroll
      for (int q = 0; q < 4; ++q)
        xv[cc][q] = xb[(size_t)(c4 * 4 + cc) * HW + w0 + 32 * q];
#pragma unroll
    for (int j = 0; j < 8; ++j) {
      float4 wv = *(const float4*)&wls[(og * 8 + j) * 256 + c4 * 4];
#pragma unroll
      for (int q = 0; q < 4; ++q)
        acc[j][q] += wv.x * xv[0][q] + wv.y * xv[1][q] + wv.z * xv[2][q] + wv.w * xv[3][q];
    }
  }

  const int obase = ohalf * 64 + og * 8;
#pragma unroll
  for (int j = 0; j < 8; ++j) {
    int o = obase + j;
    float sv = sd[o], tv = td[o], bv = b_ds[o];
#pragma unroll
    for (int q = 0; q < 4; ++q) {
      int w = w0 + 32 * q;
      float v = sv * (acc[j][q] + bv) + tv;
      identb[(size_t)(((b * 128 + o) * 128 + h)) * 128 + w] = f2bf(v);
    }
  }
}

// ---------------------------------------------------------------------------
// K3: offset conv 3x3 (128 -> 27ch) from out1T (NCHW bf16) -> offs fp32
// offs layout [b][h][w][27]: ch 0-8 dy, 9-17 dx, 18-26 sigmoid(mask)
// ---------------------------------------------------------------------------
__global__ __launch_bounds__(256) void k_off(const u16* __restrict__ out1T,
                                             const float* __restrict__ w_off,  // [27][128][3][3] fp32
                                             const float* __restrict__ b_off,
                                             float* __restrict__ offs) {
  const int tid = threadIdx.x;
  const int h = blockIdx.x, b = blockIdx.y;
  const int wave = tid >> 6, lane = tid & 63;
  const int ic_sub = lane >> 4, wg = lane & 15;

  float acc[7][8];
#pragma unroll
  for (int j = 0; j < 7; ++j)
#pragma unroll
    for (int m = 0; m < 8; ++m) acc[j][m] = 0.f;

  for (int r = 0; r < 3; ++r) {
    int hy = h + r - 1;
    if (hy < 0 || hy > 127) continue;
    for (int ic4 = 0; ic4 < 32; ++ic4) {
      int ic = ic4 * 4 + ic_sub;
      const u16* rp = out1T + (size_t)(((b * 128 + ic) * 128 + hy)) * 128 + wg * 8;
      uint4 cv = *(const uint4*)rp;
      float v[10];
      v[0] = wg ? b2f(rp[-1]) : 0.f;
      v[9] = (wg < 15) ? b2f(rp[8]) : 0.f;
      v[1] = bflo(cv.x); v[2] = bfhi(cv.x);
      v[3] = bflo(cv.y); v[4] = bfhi(cv.y);
      v[5] = bflo(cv.z); v[6] = bfhi(cv.z);
      v[7] = bflo(cv.w); v[8] = bfhi(cv.w);
      const float* wb = w_off + ic * 9 + r * 3;
#pragma unroll
      for (int j = 0; j < 7; ++j) {
        int oc = wave + 4 * j;
        if (oc < 27) {
          const float* wp = wb + oc * 1152;
          float k0 = wp[0], k1 = wp[1], k2 = wp[2];
#pragma unroll
          for (int m = 0; m < 8; ++m)
            acc[j][m] += k0 * v[m] + k1 * v[m + 1] + k2 * v[m + 2];
        }
      }
    }
  }

#pragma unroll
  for (int j = 0; j < 7; ++j)
#pragma unroll
    for (int m = 0; m < 8; ++m) {
      float t = acc[j][m];
      t += __shfl_xor(t, 16, 64);
      t += __shfl_xor(t, 32, 64);
      acc[j][m] = t;
    }

  if (ic_sub == 0) {
#pragma unroll
    for (int j = 0; j < 7; ++j) {
      int oc = wave + 4 * j;
      if (oc < 27) {
        float bo = b_off[oc];
#pragma unroll
        for (int m = 0; m < 8; ++m) {
          int wx = wg * 8 + m;
          float v = acc[j][m] + bo;
          if (oc >= 18) v = 1.f / (1.f + __expf(-v));
          offs[(size_t)(((b * 128 + h) * 128 + wx)) * 27 + oc] = v;
        }
      }
    }
  }
}

// ---------------------------------------------------------------------------
// K4: DCNv2 sampling + K=1152 GEMM + bias + bn2 + relu -> dc NHWC bf16
// grid (8, 128, 4) = (w-group of 16, h, b); block 256
// ---------------------------------------------------------------------------
__global__ __launch_bounds__(256) void k_dcn(const u16* __restrict__ out1,  // NHWC bf16
                                             const float* __restrict__ offs,
                                             const float* __restrict__ wT,  // [o][k][i] fp32
                                             const float* __restrict__ b_dc,
                                             const float* __restrict__ s2, const float* __restrict__ t2,
                                             u16* __restrict__ dc)         // NHWC bf16
{
  __shared__ __align__(16) u16 smp[16 * 1160];   // [t][k*128+c], pitch 1160
  const int tid = threadIdx.x;
  const int wq = blockIdx.x, h = blockIdx.y, b = blockIdx.z;
  const int wave = tid >> 6, lane = tid & 63;

  const float* offp = offs + (size_t)((b * 128 + h) * 128) * 27;
  const u16* base = out1 + (size_t)b * HW * 128;

  for (int p = wave; p < 144; p += 4) {
    int t = p / 9, k = p % 9;
    int w = wq * 16 + t;
    float dy = offp[w * 27 + k];
    float dx = offp[w * 27 + 9 + k];
    float mk = offp[w * 27 + 18 + k];
    float py = (float)(h - 1 + k / 3) + dy;
    float px = (float)(w - 1 + k % 3) + dx;
    float fy = floorf(py), fx = floorf(px);
    int y0 = (int)fy, x0 = (int)fx;
    float wy = py - fy, wxf = px - fx;
    float w00 = (1.f - wy) * (1.f - wxf), w01 = (1.f - wy) * wxf;
    float w10 = wy * (1.f - wxf), w11 = wy * wxf;
    bool vy0 = (y0 >= 0) && (y0 < 128), vy1 = (y0 + 1 >= 0) && (y0 + 1 < 128);
    bool vx0 = (x0 >= 0) && (x0 < 128), vx1 = (x0 + 1 >= 0) && (x0 + 1 < 128);
#pragma unroll
    for (int cc = 0; cc < 2; ++cc) {
      int c = lane + 64 * cc;
      float s = 0.f;
      if (vy0 && vx0) s += w00 * b2f(base[(size_t)((y0 * 128 + x0)) * 128 + c]);
      if (vy0 && vx1) s += w01 * b2f(base[(size_t)((y0 * 128 + x0 + 1)) * 128 + c]);
      if (vy1 && vx0) s += w10 * b2f(base[(size_t)(((y0 + 1) * 128 + x0)) * 128 + c]);
      if (vy1 && vx1) s += w11 * b2f(base[(size_t)(((y0 + 1) * 128 + x0 + 1)) * 128 + c]);
      smp[t * 1160 + k * 128 + c] = f2bf(s * mk);
    }
  }
  __syncthreads();

  const int t = tid & 15, og = tid >> 4;   // 16 o-groups x 8 o
  float acc[8];
#pragma unroll
  for (int j = 0; j < 8; ++j) acc[j] = 0.f;

  for (int k = 0; k < 9; ++k) {
    for (int c8 = 0; c8 < 16; ++c8) {
      uint4 sv = *(const uint4*)&smp[t * 1160 + k * 128 + c8 * 8];
      float xs[8];
      xs[0] = bflo(sv.x); xs[1] = bfhi(sv.x);
      xs[2] = bflo(sv.y); xs[3] = bfhi(sv.y);
      xs[4] = bflo(sv.z); xs[5] = bfhi(sv.z);
      xs[6] = bflo(sv.w); xs[7] = bfhi(sv.w);
#pragma unroll
      for (int j = 0; j < 8; ++j) {
        const float* wp = wT + (size_t)(((og * 8 + j) * 9 + k)) * 128 + c8 * 8;
        float4 wa = *(const float4*)wp;
        float4 wb = *(const float4*)(wp + 4);
        acc[j] += wa.x * xs[0] + wa.y * xs[1] + wa.z * xs[2] + wa.w * xs[3]
                + wb.x * xs[4] + wb.y * xs[5] + wb.z * xs[6] + wb.w * xs[7];
      }
    }
  }

  int w = wq * 16 + t;
  size_t pos = (size_t)((b * 128 + h) * 128 + w);
  float vv[8];
#pragma unroll
  for (int j = 0; j < 8; ++j) {
    int o = og * 8 + j;
    float v = acc[j] + b_dc[o];
    v = fmaxf(s2[o] * v + t2[o], 0.f);
    vv[j] = v;
  }
  uint4 pk;
  pk.x = pk2(vv[0], vv[1]);
  pk.y = pk2(vv[2], vv[3]);
  pk.z = pk2(vv[4], vv[5]);
  pk.w = pk2(vv[6], vv[7]);
  *(uint4*)&dc[pos * 128 + og * 8] = pk;
}

// ---------------------------------------------------------------------------
// K5: conv3 1x1 (K=128) + bn3a+relu + bn3b + ident + relu -> out NCHW fp32
// grid (128, 4) = (h, b); block 256
// ---------------------------------------------------------------------------
__global__ __launch_bounds__(256) void k_conv3(const u16* __restrict__ dc,   // NHWC bf16
                                               const float* __restrict__ w3,
                                               const float* __restrict__ s3a, const float* __restrict__ t3a,
                                               const float* __restrict__ s3b, const float* __restrict__ t3b,
                                               const u16* __restrict__ identb,
                                               float* __restrict__ out) {
  __shared__ __align__(16) float w3s[128 * 128];
  const int tid = threadIdx.x;
  const int h = blockIdx.x, b = blockIdx.y;
  {
    const float4* w4 = (const float4*)w3;
    float4* wl4 = (float4*)w3s;
#pragma unroll
    for (int i = 0; i < 16; ++i) wl4[i * 256 + tid] = w4[i * 256 + tid];
  }
  __syncthreads();

  const int w0 = tid & 31, og = tid >> 5;   // 8 groups x 16 o
  float acc[16][4];
#pragma unroll
  for (int j = 0; j < 16; ++j)
#pragma unroll
    for (int q = 0; q < 4; ++q) acc[j][q] = 0.f;

  const u16* dcp = dc + (size_t)((b * 128 + h) * 128) * 128;
  for (int c8 = 0; c8 < 16; ++c8) {
    float xs[4][8];
#pragma unroll
    for (int q = 0; q < 4; ++q) {
      uint4 sv = *(const uint4*)&dcp[(w0 + 32 * q) * 128 + c8 * 8];
      xs[q][0] = bflo(sv.x); xs[q][1] = bfhi(sv.x);
      xs[q][2] = bflo(sv.y); xs[q][3] = bfhi(sv.y);
      xs[q][4] = bflo(sv.z); xs[q][5] = bfhi(sv.z);
      xs[q][6] = bflo(sv.w); xs[q][7] = bfhi(sv.w);
    }
#pragma unroll
    for (int j = 0; j < 16; ++j) {
      const float* wp = &w3s[(og * 16 + j) * 128 + c8 * 8];
      float4 wa = *(const float4*)wp;
      float4 wb = *(const float4*)(wp + 4);
#pragma unroll
      for (int q = 0; q < 4; ++q)
        acc[j][q] += wa.x * xs[q][0] + wa.y * xs[q][1] + wa.z * xs[q][2] + wa.w * xs[q][3]
                   + wb.x * xs[q][4] + wb.y * xs[q][5] + wb.z * xs[q][6] + wb.w * xs[q][7];
    }
  }

#pragma unroll
  for (int j = 0; j < 16; ++j) {
    int o = og * 16 + j;
    float sa = s3a[o], ta = t3a[o];
    float sb = s3b[o], tb = t3b[o];
#pragma unroll
    for (int q = 0; q < 4; ++q) {
      int w = w0 + 32 * q;
      size_t idx = (size_t)(((b * 128 + o) * 128 + h)) * 128 + w;
      float v = acc[j][q];
      v = fmaxf(sa * v + ta, 0.f);
      v = sb * v + tb;
      v += b2f(identb[idx]);
      v = fmaxf(v, 0.f);
      out[idx] = v;
    }
  }
}

// ---------------------------------------------------------------------------
extern "C" void kernel_launch(void* const* d_in, const int* in_sizes, int n_in,
                              void* d_out, int out_size, void* d_ws, size_t ws_size,
                              hipStream_t stream) {
  const float* x     = (const float*)d_in[0];
  const float* w1    = (const float*)d_in[1];
  const float* s1a   = (const float*)d_in[2];
  const float* t1a   = (const float*)d_in[3];
  const float* s1b   = (const float*)d_in[4];
  const float* t1b   = (const float*)d_in[5];
  const float* w_off = (const float*)d_in[6];
  const float* b_off = (const float*)d_in[7];
  const float* w_dc  = (const float*)d_in[8];
  const float* b_dc  = (const float*)d_in[9];
  const float* s2    = (const float*)d_in[10];
  const float* t2    = (const float*)d_in[11];
  const float* w3    = (const float*)d_in[12];
  const float* s3a   = (const float*)d_in[13];
  const float* t3a   = (const float*)d_in[14];
  const float* s3b   = (const float*)d_in[15];
  const float* t3b   = (const float*)d_in[16];
  const float* w_ds  = (const float*)d_in[17];
  const float* b_ds  = (const float*)d_in[18];
  const float* sd    = (const float*)d_in[19];
  const float* td    = (const float*)d_in[20];

  // Workspace layout (total 57,999,360 B ≈ 55.3 MB).
  // out1T (bf16 NCHW, 16.8 MB) is staged in d_out (fp32 out = 33.5 MB):
  // consumed by k_off, long before k_conv3 overwrites d_out with the result.
  char* ws = (char*)d_ws;
  float* wT     = (float*)(ws + 0);          //    589,824 B  fp32 w_dc [o][k][i]
  float* offs   = (float*)(ws + 589824);     //  7,077,888 B  [b][h][w][27] fp32
  u16*   out1   = (u16*)(ws + 7667712);      // 16,777,216 B  NHWC bf16
  u16*   dc     = (u16*)(ws + 24444928);     // 16,777,216 B  NHWC bf16
  u16*   identb = (u16*)(ws + 41222144);     // 16,777,216 B  NCHW bf16
  u16*   out1T  = (u16*)d_out;               // NCHW bf16 (temporary alias)

  k_init <<<576, 256, 0, stream>>>(w_dc, wT);
  k_conv1<<<dim3(2, 128, 4), 256, 0, stream>>>(x, w1, s1a, t1a, s1b, t1b, out1, out1T);
  k_ident<<<dim3(2, 128, 4), 256, 0, stream>>>(x, w_ds, b_ds, sd, td, identb);
  k_off  <<<dim3(128, 4), 256, 0, stream>>>(out1T, w_off, b_off, offs);
  k_dcn  <<<dim3(8, 128, 4), 256, 0, stream>>>(out1, offs, wT, b_dc, s2, t2, dc);
  k_conv3<<<dim3(128, 4), 256, 0, stream>>>(dc, w3, s3a, t3a, s3b, t3b, identb, (float*)d_out);
}

// Round 4
// 761.469 us; speedup vs baseline: 2.2185x; 2.2185x over previous
//
#include <hip/hip_runtime.h>
#include <hip/hip_bf16.h>

#define HW 16384   // 128*128

typedef unsigned short u16;
typedef unsigned int   u32;
typedef __attribute__((ext_vector_type(8))) short short8v;
typedef __attribute__((ext_vector_type(4))) float float4v;

__device__ __forceinline__ float b2f(u16 v) { return __uint_as_float((u32)v << 16); }
__device__ __forceinline__ u16 f2bf(float f) {
  u32 u = __float_as_uint(f);
  u32 r = (u + 0x7fffu + ((u >> 16) & 1u)) >> 16;
  return (u16)r;
}
__device__ __forceinline__ float bflo(u32 u) { return __uint_as_float(u << 16); }
__device__ __forceinline__ float bfhi(u32 u) { return __uint_as_float(u & 0xffff0000u); }
__device__ __forceinline__ u32 pk2(float a, float b) { return ((u32)f2bf(b) << 16) | (u32)f2bf(a); }

// ---------------------------------------------------------------------------
// K0: swizzle w_dc (fp32 [o][ci][tap]) -> wTb bf16 in MFMA-B fragment order:
//     wTb[((ntile*36 + kstep)*64 + lane)*8 + j]
//     where o = ntile*16 + (lane&15), k = kstep*32 + (lane>>4)*8 + j,
//           tap = k>>7, ci = k&127   (global K index k = tap*128 + ci)
// ---------------------------------------------------------------------------
__global__ __launch_bounds__(256) void k_init(const float* __restrict__ w_dc,
                                              u16* __restrict__ wTb) {
  int idx = blockIdx.x * 256 + threadIdx.x;
  if (idx < 147456) {
    int ntile = idx / 18432, r = idx % 18432;
    int kstep = r / 512, r2 = r % 512;
    int lane = r2 / 8, j = r2 % 8;
    int o = ntile * 16 + (lane & 15);
    int k = kstep * 32 + ((lane >> 4) * 8) + j;
    int tap = k >> 7, ci = k & 127;
    wTb[idx] = f2bf(w_dc[(o * 128 + ci) * 9 + tap]);
  }
}

// ---------------------------------------------------------------------------
// K1: conv1 1x1 (K=256) + bn1a+relu + bn1b+relu -> out1 NHWC bf16 + NCHW bf16
// grid (2, 128, 4) = (o-half, h, b); block 256
// out1T lives in d_out (consumed by k_off before k_conv3 overwrites d_out).
// ---------------------------------------------------------------------------
__global__ __launch_bounds__(256) void k_conv1(const float* __restrict__ x,
                                               const float* __restrict__ w1,
                                               const float* __restrict__ s1a, const float* __restrict__ t1a,
                                               const float* __restrict__ s1b, const float* __restrict__ t1b,
                                               u16* __restrict__ out1,   // [b][h][w][o]
                                               u16* __restrict__ out1T)  // [b][o][h][w]
{
  __shared__ __align__(16) float wls[64 * 256];
  const int tid = threadIdx.x;
  const int ohalf = blockIdx.x, h = blockIdx.y, b = blockIdx.z;
  {
    const float4* w4 = (const float4*)(w1 + ohalf * 16384);
    float4* wl4 = (float4*)wls;
#pragma unroll
    for (int i = 0; i < 16; ++i) wl4[i * 256 + tid] = w4[i * 256 + tid];
  }
  __syncthreads();

  const int w0 = tid & 31, og = tid >> 5;   // 8 groups x 8 o
  float acc[8][4];
#pragma unroll
  for (int j = 0; j < 8; ++j)
#pragma unroll
    for (int q = 0; q < 4; ++q) acc[j][q] = 0.f;

  const float* xb = x + (size_t)b * 256 * HW + h * 128;
  for (int c4 = 0; c4 < 64; ++c4) {
    float xv[4][4];
#pragma unroll
    for (int cc = 0; cc < 4; ++cc)
#pragma unroll
      for (int q = 0; q < 4; ++q)
        xv[cc][q] = xb[(size_t)(c4 * 4 + cc) * HW + w0 + 32 * q];
#pragma unroll
    for (int j = 0; j < 8; ++j) {
      float4 wv = *(const float4*)&wls[(og * 8 + j) * 256 + c4 * 4];
#pragma unroll
      for (int q = 0; q < 4; ++q)
        acc[j][q] += wv.x * xv[0][q] + wv.y * xv[1][q] + wv.z * xv[2][q] + wv.w * xv[3][q];
    }
  }

  const int obase = ohalf * 64 + og * 8;
#pragma unroll
  for (int j = 0; j < 8; ++j) {
    int o = obase + j;
    float sa = s1a[o], ta = t1a[o];
    float sb = s1b[o], tb = t1b[o];
#pragma unroll
    for (int q = 0; q < 4; ++q) {
      float v = acc[j][q];
      v = fmaxf(sa * v + ta, 0.f);
      v = fmaxf(sb * v + tb, 0.f);
      acc[j][q] = v;
    }
  }
#pragma unroll
  for (int q = 0; q < 4; ++q) {
    int w = w0 + 32 * q;
    size_t pos = (size_t)((b * 128 + h) * 128 + w);
    uint4 pk;
    pk.x = pk2(acc[0][q], acc[1][q]);
    pk.y = pk2(acc[2][q], acc[3][q]);
    pk.z = pk2(acc[4][q], acc[5][q]);
    pk.w = pk2(acc[6][q], acc[7][q]);
    *(uint4*)&out1[pos * 128 + obase] = pk;
#pragma unroll
    for (int j = 0; j < 8; ++j)
      out1T[(size_t)(((b * 128 + obase + j) * 128 + h)) * 128 + w] = f2bf(acc[j][q]);
  }
}

// ---------------------------------------------------------------------------
// K2: downsample 1x1 (K=256): ident = sd*(conv + b_ds) + td  -> NCHW bf16
// ---------------------------------------------------------------------------
__global__ __launch_bounds__(256) void k_ident(const float* __restrict__ x,
                                               const float* __restrict__ w_ds,
                                               const float* __restrict__ b_ds,
                                               const float* __restrict__ sd, const float* __restrict__ td,
                                               u16* __restrict__ identb) {
  __shared__ __align__(16) float wls[64 * 256];
  const int tid = threadIdx.x;
  const int ohalf = blockIdx.x, h = blockIdx.y, b = blockIdx.z;
  {
    const float4* w4 = (const float4*)(w_ds + ohalf * 16384);
    float4* wl4 = (float4*)wls;
#pragma unroll
    for (int i = 0; i < 16; ++i) wl4[i * 256 + tid] = w4[i * 256 + tid];
  }
  __syncthreads();

  const int w0 = tid & 31, og = tid >> 5;
  float acc[8][4];
#pragma unroll
  for (int j = 0; j < 8; ++j)
#pragma unroll
    for (int q = 0; q < 4; ++q) acc[j][q] = 0.f;

  const float* xb = x + (size_t)b * 256 * HW + h * 128;
  for (int c4 = 0; c4 < 64; ++c4) {
    float xv[4][4];
#pragma unroll
    for (int cc = 0; cc < 4; ++cc)
#pragma unroll
      for (int q = 0; q < 4; ++q)
        xv[cc][q] = xb[(size_t)(c4 * 4 + cc) * HW + w0 + 32 * q];
#pragma unroll
    for (int j = 0; j < 8; ++j) {
      float4 wv = *(const float4*)&wls[(og * 8 + j) * 256 + c4 * 4];
#pragma unroll
      for (int q = 0; q < 4; ++q)
        acc[j][q] += wv.x * xv[0][q] + wv.y * xv[1][q] + wv.z * xv[2][q] + wv.w * xv[3][q];
    }
  }

  const int obase = ohalf * 64 + og * 8;
#pragma unroll
  for (int j = 0; j < 8; ++j) {
    int o = obase + j;
    float sv = sd[o], tv = td[o], bv = b_ds[o];
#pragma unroll
    for (int q = 0; q < 4; ++q) {
      int w = w0 + 32 * q;
      float v = sv * (acc[j][q] + bv) + tv;
      identb[(size_t)(((b * 128 + o) * 128 + h)) * 128 + w] = f2bf(v);
    }
  }
}

// ---------------------------------------------------------------------------
// K3: offset conv 3x3 (128 -> 27ch) from out1T (NCHW bf16) -> offs fp32
// offs layout [b][h][w][27]: ch 0-8 dy, 9-17 dx, 18-26 sigmoid(mask)
// ---------------------------------------------------------------------------
__global__ __launch_bounds__(256) void k_off(const u16* __restrict__ out1T,
                                             const float* __restrict__ w_off,  // [27][128][3][3] fp32
                                             const float* __restrict__ b_off,
                                             float* __restrict__ offs) {
  const int tid = threadIdx.x;
  const int h = blockIdx.x, b = blockIdx.y;
  const int wave = tid >> 6, lane = tid & 63;
  const int ic_sub = lane >> 4, wg = lane & 15;

  float acc[7][8];
#pragma unroll
  for (int j = 0; j < 7; ++j)
#pragma unroll
    for (int m = 0; m < 8; ++m) acc[j][m] = 0.f;

  for (int r = 0; r < 3; ++r) {
    int hy = h + r - 1;
    if (hy < 0 || hy > 127) continue;
    for (int ic4 = 0; ic4 < 32; ++ic4) {
      int ic = ic4 * 4 + ic_sub;
      const u16* rp = out1T + (size_t)(((b * 128 + ic) * 128 + hy)) * 128 + wg * 8;
      uint4 cv = *(const uint4*)rp;
      float v[10];
      v[0] = wg ? b2f(rp[-1]) : 0.f;
      v[9] = (wg < 15) ? b2f(rp[8]) : 0.f;
      v[1] = bflo(cv.x); v[2] = bfhi(cv.x);
      v[3] = bflo(cv.y); v[4] = bfhi(cv.y);
      v[5] = bflo(cv.z); v[6] = bfhi(cv.z);
      v[7] = bflo(cv.w); v[8] = bfhi(cv.w);
      const float* wb = w_off + ic * 9 + r * 3;
#pragma unroll
      for (int j = 0; j < 7; ++j) {
        int oc = wave + 4 * j;
        if (oc < 27) {
          const float* wp = wb + oc * 1152;
          float k0 = wp[0], k1 = wp[1], k2 = wp[2];
#pragma unroll
          for (int m = 0; m < 8; ++m)
            acc[j][m] += k0 * v[m] + k1 * v[m + 1] + k2 * v[m + 2];
        }
      }
    }
  }

#pragma unroll
  for (int j = 0; j < 7; ++j)
#pragma unroll
    for (int m = 0; m < 8; ++m) {
      float t = acc[j][m];
      t += __shfl_xor(t, 16, 64);
      t += __shfl_xor(t, 32, 64);
      acc[j][m] = t;
    }

  if (ic_sub == 0) {
#pragma unroll
    for (int j = 0; j < 7; ++j) {
      int oc = wave + 4 * j;
      if (oc < 27) {
        float bo = b_off[oc];
#pragma unroll
        for (int m = 0; m < 8; ++m) {
          int wx = wg * 8 + m;
          float v = acc[j][m] + bo;
          if (oc >= 18) v = 1.f / (1.f + __expf(-v));
          offs[(size_t)(((b * 128 + h) * 128 + wx)) * 27 + oc] = v;
        }
      }
    }
  }
}

// ---------------------------------------------------------------------------
// K4: DCNv2 sampling + MFMA GEMM (M=32 pos, N=128 o, K=1152) + bn2 + relu
// grid (4, 128, 4) = (w-group of 32, h, b); block 256 = 4 waves
// Phase 1: bilinear-sample 32x9x128 taps into LDS, A-operand layout
//          A[m=pos][k=tap*128+c], row pitch 1160 u16 (2-way bank alias = free)
// Phase 2: mfma_f32_16x16x32_bf16; wave handles 2 M-tiles x 2 N-tiles;
//          B frags loaded coalesced from pre-swizzled wTb (global, L2-hot)
// ---------------------------------------------------------------------------
__global__ __launch_bounds__(256) void k_dcn(const u16* __restrict__ out1,  // NHWC bf16
                                             const float* __restrict__ offs,
                                             const u16* __restrict__ wTb,   // swizzled bf16 B
                                             const float* __restrict__ b_dc,
                                             const float* __restrict__ s2, const float* __restrict__ t2,
                                             u16* __restrict__ dc)         // NHWC bf16
{
  __shared__ __align__(16) u16 Alds[32 * 1160];   // 74,240 B
  const int tid = threadIdx.x;
  const int wq = blockIdx.x, h = blockIdx.y, b = blockIdx.z;
  const int wave = tid >> 6, lane = tid & 63;

  const float* offp = offs + (size_t)((b * 128 + h) * 128) * 27;
  const u16* base = out1 + (size_t)b * HW * 128;

  // ---- Phase 1: sampling. 288 jobs (pos,tap), 4 waves round-robin. ----
  for (int job = wave; job < 288; job += 4) {
    int pos = job / 9, tap = job % 9;
    int w = wq * 32 + pos;
    float dy = offp[w * 27 + tap];
    float dx = offp[w * 27 + 9 + tap];
    float mk = offp[w * 27 + 18 + tap];
    float py = (float)(h - 1 + tap / 3) + dy;
    float px = (float)(w - 1 + tap % 3) + dx;
    float fy = floorf(py), fx = floorf(px);
    int y0 = (int)fy, x0 = (int)fx;
    float wy = py - fy, wxf = px - fx;
    float w00 = (1.f - wy) * (1.f - wxf), w01 = (1.f - wy) * wxf;
    float w10 = wy * (1.f - wxf), w11 = wy * wxf;
    bool vy0 = (y0 >= 0) && (y0 < 128), vy1 = (y0 + 1 >= 0) && (y0 + 1 < 128);
    bool vx0 = (x0 >= 0) && (x0 < 128), vx1 = (x0 + 1 >= 0) && (x0 + 1 < 128);
    int c = lane * 2;
    float lo = 0.f, hi = 0.f;
    if (vy0 && vx0) { u32 v = *(const u32*)&base[(size_t)(y0 * 128 + x0) * 128 + c];       lo += w00 * bflo(v); hi += w00 * bfhi(v); }
    if (vy0 && vx1) { u32 v = *(const u32*)&base[(size_t)(y0 * 128 + x0 + 1) * 128 + c];   lo += w01 * bflo(v); hi += w01 * bfhi(v); }
    if (vy1 && vx0) { u32 v = *(const u32*)&base[(size_t)((y0 + 1) * 128 + x0) * 128 + c]; lo += w10 * bflo(v); hi += w10 * bfhi(v); }
    if (vy1 && vx1) { u32 v = *(const u32*)&base[(size_t)((y0 + 1) * 128 + x0 + 1) * 128 + c]; lo += w11 * bflo(v); hi += w11 * bfhi(v); }
    lo *= mk; hi *= mk;
    *(u32*)&Alds[pos * 1160 + tap * 128 + c] = pk2(lo, hi);
  }
  __syncthreads();

  // ---- Phase 2: MFMA GEMM ----
  const int nlo = lane & 15, kgr = lane >> 4;
  float4v acc[2][2];
#pragma unroll
  for (int mt = 0; mt < 2; ++mt)
#pragma unroll
    for (int nt = 0; nt < 2; ++nt) acc[mt][nt] = (float4v)(0.f);

  const u16* a_base0 = &Alds[nlo * 1160 + kgr * 8];
  const u16* a_base1 = &Alds[(nlo + 16) * 1160 + kgr * 8];
  const u16* b_base0 = &wTb[(((size_t)(wave * 2 + 0) * 36) * 64 + lane) * 8];
  const u16* b_base1 = &wTb[(((size_t)(wave * 2 + 1) * 36) * 64 + lane) * 8];

  for (int ks = 0; ks < 36; ++ks) {
    short8v a0 = *(const short8v*)(a_base0 + ks * 32);
    short8v a1 = *(const short8v*)(a_base1 + ks * 32);
    short8v b0 = *(const short8v*)(b_base0 + (size_t)ks * 512);
    short8v b1 = *(const short8v*)(b_base1 + (size_t)ks * 512);
    acc[0][0] = __builtin_amdgcn_mfma_f32_16x16x32_bf16(a0, b0, acc[0][0], 0, 0, 0);
    acc[0][1] = __builtin_amdgcn_mfma_f32_16x16x32_bf16(a0, b1, acc[0][1], 0, 0, 0);
    acc[1][0] = __builtin_amdgcn_mfma_f32_16x16x32_bf16(a1, b0, acc[1][0], 0, 0, 0);
    acc[1][1] = __builtin_amdgcn_mfma_f32_16x16x32_bf16(a1, b1, acc[1][1], 0, 0, 0);
  }

  // ---- Epilogue: D[m][n]: n = lane&15, m = (lane>>4)*4 + reg ----
  const int rbase = kgr * 4;
#pragma unroll
  for (int nt = 0; nt < 2; ++nt) {
    int o = (wave * 2 + nt) * 16 + nlo;
    float bd = b_dc[o], ss = s2[o], tt = t2[o];
#pragma unroll
    for (int mt = 0; mt < 2; ++mt) {
#pragma unroll
      for (int r = 0; r < 4; ++r) {
        int w = wq * 32 + mt * 16 + rbase + r;
        float v = acc[mt][nt][r] + bd;
        v = fmaxf(ss * v + tt, 0.f);
        dc[((size_t)((b * 128 + h) * 128 + w)) * 128 + o] = f2bf(v);
      }
    }
  }
}

// ---------------------------------------------------------------------------
// K5: conv3 1x1 (K=128) + bn3a+relu + bn3b + ident + relu -> out NCHW fp32
// grid (128, 4) = (h, b); block 256
// ---------------------------------------------------------------------------
__global__ __launch_bounds__(256) void k_conv3(const u16* __restrict__ dc,   // NHWC bf16
                                               const float* __restrict__ w3,
                                               const float* __restrict__ s3a, const float* __restrict__ t3a,
                                               const float* __restrict__ s3b, const float* __restrict__ t3b,
                                               const u16* __restrict__ identb,
                                               float* __restrict__ out) {
  __shared__ __align__(16) float w3s[128 * 128];
  const int tid = threadIdx.x;
  const int h = blockIdx.x, b = blockIdx.y;
  {
    const float4* w4 = (const float4*)w3;
    float4* wl4 = (float4*)w3s;
#pragma unroll
    for (int i = 0; i < 16; ++i) wl4[i * 256 + tid] = w4[i * 256 + tid];
  }
  __syncthreads();

  const int w0 = tid & 31, og = tid >> 5;   // 8 groups x 16 o
  float acc[16][4];
#pragma unroll
  for (int j = 0; j < 16; ++j)
#pragma unroll
    for (int q = 0; q < 4; ++q) acc[j][q] = 0.f;

  const u16* dcp = dc + (size_t)((b * 128 + h) * 128) * 128;
  for (int c8 = 0; c8 < 16; ++c8) {
    float xs[4][8];
#pragma unroll
    for (int q = 0; q < 4; ++q) {
      uint4 sv = *(const uint4*)&dcp[(w0 + 32 * q) * 128 + c8 * 8];
      xs[q][0] = bflo(sv.x); xs[q][1] = bfhi(sv.x);
      xs[q][2] = bflo(sv.y); xs[q][3] = bfhi(sv.y);
      xs[q][4] = bflo(sv.z); xs[q][5] = bfhi(sv.z);
      xs[q][6] = bflo(sv.w); xs[q][7] = bfhi(sv.w);
    }
#pragma unroll
    for (int j = 0; j < 16; ++j) {
      const float* wp = &w3s[(og * 16 + j) * 128 + c8 * 8];
      float4 wa = *(const float4*)wp;
      float4 wb = *(const float4*)(wp + 4);
#pragma unroll
      for (int q = 0; q < 4; ++q)
        acc[j][q] += wa.x * xs[q][0] + wa.y * xs[q][1] + wa.z * xs[q][2] + wa.w * xs[q][3]
                   + wb.x * xs[q][4] + wb.y * xs[q][5] + wb.z * xs[q][6] + wb.w * xs[q][7];
    }
  }

#pragma unroll
  for (int j = 0; j < 16; ++j) {
    int o = og * 16 + j;
    float sa = s3a[o], ta = t3a[o];
    float sb = s3b[o], tb = t3b[o];
#pragma unroll
    for (int q = 0; q < 4; ++q) {
      int w = w0 + 32 * q;
      size_t idx = (size_t)(((b * 128 + o) * 128 + h)) * 128 + w;
      float v = acc[j][q];
      v = fmaxf(sa * v + ta, 0.f);
      v = sb * v + tb;
      v += b2f(identb[idx]);
      v = fmaxf(v, 0.f);
      out[idx] = v;
    }
  }
}

// ---------------------------------------------------------------------------
extern "C" void kernel_launch(void* const* d_in, const int* in_sizes, int n_in,
                              void* d_out, int out_size, void* d_ws, size_t ws_size,
                              hipStream_t stream) {
  const float* x     = (const float*)d_in[0];
  const float* w1    = (const float*)d_in[1];
  const float* s1a   = (const float*)d_in[2];
  const float* t1a   = (const float*)d_in[3];
  const float* s1b   = (const float*)d_in[4];
  const float* t1b   = (const float*)d_in[5];
  const float* w_off = (const float*)d_in[6];
  const float* b_off = (const float*)d_in[7];
  const float* w_dc  = (const float*)d_in[8];
  const float* b_dc  = (const float*)d_in[9];
  const float* s2    = (const float*)d_in[10];
  const float* t2    = (const float*)d_in[11];
  const float* w3    = (const float*)d_in[12];
  const float* s3a   = (const float*)d_in[13];
  const float* t3a   = (const float*)d_in[14];
  const float* s3b   = (const float*)d_in[15];
  const float* t3b   = (const float*)d_in[16];
  const float* w_ds  = (const float*)d_in[17];
  const float* b_ds  = (const float*)d_in[18];
  const float* sd    = (const float*)d_in[19];
  const float* td    = (const float*)d_in[20];

  // Workspace layout (≈55.3 MB total).
  // out1T (bf16 NCHW, 16.8 MB) is staged in d_out (fp32 out = 33.5 MB):
  // consumed by k_off, long before k_conv3 overwrites d_out with the result.
  char* ws = (char*)d_ws;
  u16*   wTb    = (u16*)(ws + 0);            //    294,912 B  bf16 w_dc, MFMA-B swizzled
  float* offs   = (float*)(ws + 589824);     //  7,077,888 B  [b][h][w][27] fp32
  u16*   out1   = (u16*)(ws + 7667712);      // 16,777,216 B  NHWC bf16
  u16*   dc     = (u16*)(ws + 24444928);     // 16,777,216 B  NHWC bf16
  u16*   identb = (u16*)(ws + 41222144);     // 16,777,216 B  NCHW bf16
  u16*   out1T  = (u16*)d_out;               // NCHW bf16 (temporary alias)

  k_init <<<576, 256, 0, stream>>>(w_dc, wTb);
  k_conv1<<<dim3(2, 128, 4), 256, 0, stream>>>(x, w1, s1a, t1a, s1b, t1b, out1, out1T);
  k_ident<<<dim3(2, 128, 4), 256, 0, stream>>>(x, w_ds, b_ds, sd, td, identb);
  k_off  <<<dim3(128, 4), 256, 0, stream>>>(out1T, w_off, b_off, offs);
  k_dcn  <<<dim3(4, 128, 4), 256, 0, stream>>>(out1, offs, wTb, b_dc, s2, t2, dc);
  k_conv3<<<dim3(128, 4), 256, 0, stream>>>(dc, w3, s3a, t3a, s3b, t3b, identb, (float*)d_out);
}

// Round 5
// 390.561 us; speedup vs baseline: 4.3253x; 1.9497x over previous
//
#include <hip/hip_runtime.h>
#include <hip/hip_bf16.h>

#define HW 16384   // 128*128

typedef unsigned short u16;
typedef unsigned int   u32;
typedef __attribute__((ext_vector_type(8))) short short8v;
typedef __attribute__((ext_vector_type(4))) float float4v;

__device__ __forceinline__ float b2f(u16 v) { return __uint_as_float((u32)v << 16); }
__device__ __forceinline__ u16 f2bf(float f) {
  u32 u = __float_as_uint(f);
  u32 r = (u + 0x7fffu + ((u >> 16) & 1u)) >> 16;
  return (u16)r;
}
__device__ __forceinline__ float bflo(u32 u) { return __uint_as_float(u << 16); }
__device__ __forceinline__ float bfhi(u32 u) { return __uint_as_float(u & 0xffff0000u); }
__device__ __forceinline__ u32 pk2(float a, float b) { return ((u32)f2bf(b) << 16) | (u32)f2bf(a); }

// ---------------------------------------------------------------------------
// K0: swizzle ALL weights into MFMA-B fragment order (bf16).
//  B-frag layout: buf[((ntile*KS + ks)*64 + lane)*8 + j]
//  with o = ntile*16 + (lane&15), k = ks*32 + (lane>>4)*8 + j.
//  wTb  : w_dc  N=128 K=1152 (k = tap*128 + ci)      147456 elems
//  wB1  : [w1 ; w_ds] N=256 K=256                      65536 elems
//  w3b  : w3   N=128 K=128                             16384 elems
//  woffb: w_off N=32(27 pad0) K=1152                   36864 elems
// ---------------------------------------------------------------------------
__global__ __launch_bounds__(256) void k_init(const float* __restrict__ w_dc,
                                              const float* __restrict__ w1,
                                              const float* __restrict__ w_ds,
                                              const float* __restrict__ w3,
                                              const float* __restrict__ w_off,
                                              u16* __restrict__ wTb, u16* __restrict__ wB1,
                                              u16* __restrict__ w3b, u16* __restrict__ woffb) {
  int idx = blockIdx.x * 256 + threadIdx.x;
  if (idx < 147456) {
    int ntile = idx / 18432, r = idx % 18432;
    int ks = r / 512, r2 = r % 512;
    int lane = r2 / 8, j = r2 % 8;
    int o = ntile * 16 + (lane & 15);
    int k = ks * 32 + ((lane >> 4) * 8) + j;
    int tap = k >> 7, ci = k & 127;
    wTb[idx] = f2bf(w_dc[(o * 128 + ci) * 9 + tap]);
  }
  int i1 = idx - 147456;
  if (i1 >= 0 && i1 < 65536) {
    int ntile = i1 / 4096, r = i1 % 4096;
    int ks = r / 512, r2 = r % 512;
    int lane = r2 / 8, j = r2 % 8;
    int o = ntile * 16 + (lane & 15);
    int c = ks * 32 + ((lane >> 4) * 8) + j;
    float v = (ntile < 8) ? w1[o * 256 + c] : w_ds[(o - 128) * 256 + c];
    wB1[i1] = f2bf(v);
  }
  int i2 = idx - 212992;
  if (i2 >= 0 && i2 < 16384) {
    int ntile = i2 / 2048, r = i2 % 2048;
    int ks = r / 512, r2 = r % 512;
    int lane = r2 / 8, j = r2 % 8;
    int o = ntile * 16 + (lane & 15);
    int c = ks * 32 + ((lane >> 4) * 8) + j;
    w3b[i2] = f2bf(w3[o * 128 + c]);
  }
  int i3 = idx - 229376;
  if (i3 >= 0 && i3 < 36864) {
    int ntile = i3 / 18432, r = i3 % 18432;
    int ks = r / 512, r2 = r % 512;
    int lane = r2 / 8, j = r2 % 8;
    int oc = ntile * 16 + (lane & 15);
    int k = ks * 32 + ((lane >> 4) * 8) + j;
    int tap = k >> 7, c = k & 127;
    woffb[i3] = (oc < 27) ? f2bf(w_off[oc * 1152 + c * 9 + tap]) : (u16)0;
  }
}

// ---------------------------------------------------------------------------
// K1: fused conv1+downsample MFMA GEMM. M=32 pos, N=256 (o<128 conv1 chain,
// o>=128 downsample+bn), K=256. grid (4,128,4); block 256 = 4 waves.
// Waves 0-1: conv1 ntiles 0-7 -> out1 NHWC bf16 (direct scalar stores).
// Waves 2-3: ds ntiles 8-15 -> LDS transpose -> identb NCHW bf16 coalesced.
// ---------------------------------------------------------------------------
__global__ __launch_bounds__(256) void k_fused1(const float* __restrict__ x,
                                                const u16* __restrict__ wB1,
                                                const float* __restrict__ s1a, const float* __restrict__ t1a,
                                                const float* __restrict__ s1b, const float* __restrict__ t1b,
                                                const float* __restrict__ b_ds,
                                                const float* __restrict__ sd, const float* __restrict__ td,
                                                u16* __restrict__ out1,      // [b][h][w][o]
                                                u16* __restrict__ identb)    // [b][o][h][w]
{
  __shared__ __align__(16) u16 xA[32 * 264];   // [pos][c] bf16, pitch 264
  __shared__ __align__(16) u16 T1[128 * 34];   // [o][pos] transpose buffer
  const int tid = threadIdx.x;
  const int wq = blockIdx.x, h = blockIdx.y, b = blockIdx.z;
  const int wave = tid >> 6, lane = tid & 63;

  // stage x tile (256 c x 32 w) -> bf16 transposed [pos][c]
  {
    const float* xb = x + (size_t)b * 256 * HW + h * 128 + wq * 32;
    int cr = tid >> 3, wg = tid & 7;
#pragma unroll
    for (int i = 0; i < 8; ++i) {
      int c = i * 32 + cr;
      float4 v = *(const float4*)&xb[(size_t)c * HW + wg * 4];
      int p0 = wg * 4;
      xA[(p0 + 0) * 264 + c] = f2bf(v.x);
      xA[(p0 + 1) * 264 + c] = f2bf(v.y);
      xA[(p0 + 2) * 264 + c] = f2bf(v.z);
      xA[(p0 + 3) * 264 + c] = f2bf(v.w);
    }
  }
  __syncthreads();

  const int nlo = lane & 15, kgr = lane >> 4;
  float4v acc[2][4];
#pragma unroll
  for (int mt = 0; mt < 2; ++mt)
#pragma unroll
    for (int nt = 0; nt < 4; ++nt) acc[mt][nt] = (float4v)(0.f);

  const u16* a0p = &xA[nlo * 264 + kgr * 8];
  const u16* a1p = &xA[(nlo + 16) * 264 + kgr * 8];
  const u16* bp = &wB1[(((size_t)(wave * 4) * 8) * 64 + lane) * 8];

#pragma unroll
  for (int ks = 0; ks < 8; ++ks) {
    short8v a0 = *(const short8v*)(a0p + ks * 32);
    short8v a1 = *(const short8v*)(a1p + ks * 32);
#pragma unroll
    for (int nt = 0; nt < 4; ++nt) {
      short8v bv = *(const short8v*)(bp + nt * 4096 + ks * 512);
      acc[0][nt] = __builtin_amdgcn_mfma_f32_16x16x32_bf16(a0, bv, acc[0][nt], 0, 0, 0);
      acc[1][nt] = __builtin_amdgcn_mfma_f32_16x16x32_bf16(a1, bv, acc[1][nt], 0, 0, 0);
    }
  }

  const int rbase = kgr * 4;
  if (wave < 2) {
    // conv1 chain: relu(s1a*v+t1a) then relu(s1b*v+t1b) -> out1 NHWC
#pragma unroll
    for (int nt = 0; nt < 4; ++nt) {
      int o = (wave * 4 + nt) * 16 + nlo;
      float sa = s1a[o], ta = t1a[o], sb = s1b[o], tb = t1b[o];
#pragma unroll
      for (int mt = 0; mt < 2; ++mt)
#pragma unroll
        for (int r = 0; r < 4; ++r) {
          float v = acc[mt][nt][r];
          v = fmaxf(sa * v + ta, 0.f);
          v = fmaxf(sb * v + tb, 0.f);
          int pos = mt * 16 + rbase + r;
          out1[((size_t)((b * 128 + h) * 128 + wq * 32 + pos)) * 128 + o] = f2bf(v);
        }
    }
  } else {
    // downsample: sd*(v + b_ds) + td -> T1[o][pos]
#pragma unroll
    for (int nt = 0; nt < 4; ++nt) {
      int og = (wave * 4 + nt) * 16 + nlo - 128;
      float sv = sd[og], tv = td[og], bv = b_ds[og];
#pragma unroll
      for (int mt = 0; mt < 2; ++mt)
#pragma unroll
        for (int r = 0; r < 4; ++r) {
          float v = sv * (acc[mt][nt][r] + bv) + tv;
          T1[og * 34 + mt * 16 + rbase + r] = f2bf(v);
        }
    }
  }
  __syncthreads();

  // coalesced copy T1 -> identb NCHW
  {
    int o = tid >> 1, half = tid & 1;
    const u16* src = &T1[o * 34 + half * 16];
    u32 bb[8];
#pragma unroll
    for (int i = 0; i < 8; ++i) bb[i] = *(const u32*)(src + i * 2);
    size_t g = ((size_t)((b * 128 + o) * 128 + h)) * 128 + wq * 32 + half * 16;
    uint4 p0 = make_uint4(bb[0], bb[1], bb[2], bb[3]);
    uint4 p1 = make_uint4(bb[4], bb[5], bb[6], bb[7]);
    *(uint4*)&identb[g] = p0;
    *(uint4*)&identb[g + 8] = p1;
  }
}

// ---------------------------------------------------------------------------
// K2: offset conv as im2col MFMA. M=32 pos, N=32 (27 + pad), K=1152.
// grid (4,128,4); block 256 = 4 waves; wave -> (mt,nt) = (wave>>1, wave&1).
// Output offs [b][h][w][27]: 0-8 dy, 9-17 dx, 18-26 sigmoid(mask).
// ---------------------------------------------------------------------------
__global__ __launch_bounds__(256) void k_off2(const u16* __restrict__ out1,
                                              const u16* __restrict__ woffb,
                                              const float* __restrict__ b_off,
                                              float* __restrict__ offs) {
  __shared__ __align__(16) u16 Alds[32 * 1160];
  const int tid = threadIdx.x;
  const int wq = blockIdx.x, h = blockIdx.y, b = blockIdx.z;
  const int wave = tid >> 6, lane = tid & 63;
  const u16* base = out1 + (size_t)b * HW * 128;

  for (int job = wave; job < 288; job += 4) {
    int pos = job / 9, tap = job % 9;
    int w = wq * 32 + pos;
    int yy = h + tap / 3 - 1, xx = w + tap % 3 - 1;
    int c = lane * 2;
    u32 v = 0;
    if (yy >= 0 && yy < 128 && xx >= 0 && xx < 128)
      v = *(const u32*)&base[(size_t)(yy * 128 + xx) * 128 + c];
    *(u32*)&Alds[pos * 1160 + tap * 128 + c] = v;
  }
  __syncthreads();

  const int nlo = lane & 15, kgr = lane >> 4;
  const int mt = wave >> 1, nt = wave & 1;
  float4v acc = (float4v)(0.f);
  const u16* ap = &Alds[(mt * 16 + nlo) * 1160 + kgr * 8];
  const u16* bp = &woffb[(((size_t)nt * 36) * 64 + lane) * 8];
  for (int ks = 0; ks < 36; ++ks) {
    short8v a = *(const short8v*)(ap + ks * 32);
    short8v bv = *(const short8v*)(bp + ks * 512);
    acc = __builtin_amdgcn_mfma_f32_16x16x32_bf16(a, bv, acc, 0, 0, 0);
  }

  int oc = nt * 16 + nlo;
  if (oc < 27) {
    float bo = b_off[oc];
#pragma unroll
    for (int r = 0; r < 4; ++r) {
      int w = wq * 32 + mt * 16 + kgr * 4 + r;
      float v = acc[r] + bo;
      if (oc >= 18) v = 1.f / (1.f + __expf(-v));
      offs[(size_t)((b * 128 + h) * 128 + w) * 27 + oc] = v;
    }
  }
}

// ---------------------------------------------------------------------------
// K3: DCNv2 sampling + MFMA GEMM (M=32, N=128, K=1152) + bn2 + relu.
// grid (4,128,4); block 256 = 4 waves.
// Phase 0: coalesced preload of the block's 864 offs floats into LDS.
// Phase 1: bilinear sampling with UNCONDITIONAL clamped loads (validity
//          folded into weights) -> deep load pipelining.
// Phase 2: MFMA, B frags from pre-swizzled wTb (L2-hot).
// ---------------------------------------------------------------------------
__global__ __launch_bounds__(256) void k_dcn(const u16* __restrict__ out1,
                                             const float* __restrict__ offs,
                                             const u16* __restrict__ wTb,
                                             const float* __restrict__ b_dc,
                                             const float* __restrict__ s2, const float* __restrict__ t2,
                                             u16* __restrict__ dc) {
  __shared__ __align__(16) u16 Alds[32 * 1160];
  __shared__ __align__(16) float offl[864];
  const int tid = threadIdx.x;
  const int wq = blockIdx.x, h = blockIdx.y, b = blockIdx.z;
  const int wave = tid >> 6, lane = tid & 63;
  const u16* base = out1 + (size_t)b * HW * 128;

  {
    const float* osrc = offs + ((size_t)((b * 128 + h) * 128) + wq * 32) * 27;
    for (int i = tid; i < 864; i += 256) offl[i] = osrc[i];
  }
  __syncthreads();

  for (int job = wave; job < 288; job += 4) {
    int pos = job / 9, tap = job % 9;
    int w = wq * 32 + pos;
    float dy = offl[pos * 27 + tap];
    float dxv = offl[pos * 27 + 9 + tap];
    float mk = offl[pos * 27 + 18 + tap];
    float py = (float)(h - 1 + tap / 3) + dy;
    float px = (float)(w - 1 + tap % 3) + dxv;
    float fy = floorf(py), fx = floorf(px);
    int y0 = (int)fy, x0 = (int)fx;
    float wy = py - fy, wxf = px - fx;
    bool vy0 = (y0 >= 0) & (y0 < 128), vy1 = (y0 >= -1) & (y0 < 127);
    bool vx0 = (x0 >= 0) & (x0 < 128), vx1 = (x0 >= -1) & (x0 < 127);
    float w00 = (vy0 & vx0) ? (1.f - wy) * (1.f - wxf) * mk : 0.f;
    float w01 = (vy0 & vx1) ? (1.f - wy) * wxf * mk : 0.f;
    float w10 = (vy1 & vx0) ? wy * (1.f - wxf) * mk : 0.f;
    float w11 = (vy1 & vx1) ? wy * wxf * mk : 0.f;
    int y0c = min(max(y0, 0), 127), y1c = min(max(y0 + 1, 0), 127);
    int x0c = min(max(x0, 0), 127), x1c = min(max(x0 + 1, 0), 127);
    int c = lane * 2;
    const u16* pr0 = base + (size_t)(y0c * 128) * 128 + c;
    const u16* pr1 = base + (size_t)(y1c * 128) * 128 + c;
    u32 v00 = *(const u32*)(pr0 + x0c * 128);
    u32 v01 = *(const u32*)(pr0 + x1c * 128);
    u32 v10 = *(const u32*)(pr1 + x0c * 128);
    u32 v11 = *(const u32*)(pr1 + x1c * 128);
    float lo = w00 * bflo(v00) + w01 * bflo(v01) + w10 * bflo(v10) + w11 * bflo(v11);
    float hi = w00 * bfhi(v00) + w01 * bfhi(v01) + w10 * bfhi(v10) + w11 * bfhi(v11);
    *(u32*)&Alds[pos * 1160 + tap * 128 + c] = pk2(lo, hi);
  }
  __syncthreads();

  const int nlo = lane & 15, kgr = lane >> 4;
  float4v acc[2][2];
#pragma unroll
  for (int mt = 0; mt < 2; ++mt)
#pragma unroll
    for (int nt = 0; nt < 2; ++nt) acc[mt][nt] = (float4v)(0.f);

  const u16* a_base0 = &Alds[nlo * 1160 + kgr * 8];
  const u16* a_base1 = &Alds[(nlo + 16) * 1160 + kgr * 8];
  const u16* b_base0 = &wTb[(((size_t)(wave * 2 + 0) * 36) * 64 + lane) * 8];
  const u16* b_base1 = &wTb[(((size_t)(wave * 2 + 1) * 36) * 64 + lane) * 8];

  for (int ks = 0; ks < 36; ++ks) {
    short8v a0 = *(const short8v*)(a_base0 + ks * 32);
    short8v a1 = *(const short8v*)(a_base1 + ks * 32);
    short8v b0 = *(const short8v*)(b_base0 + (size_t)ks * 512);
    short8v b1 = *(const short8v*)(b_base1 + (size_t)ks * 512);
    acc[0][0] = __builtin_amdgcn_mfma_f32_16x16x32_bf16(a0, b0, acc[0][0], 0, 0, 0);
    acc[0][1] = __builtin_amdgcn_mfma_f32_16x16x32_bf16(a0, b1, acc[0][1], 0, 0, 0);
    acc[1][0] = __builtin_amdgcn_mfma_f32_16x16x32_bf16(a1, b0, acc[1][0], 0, 0, 0);
    acc[1][1] = __builtin_amdgcn_mfma_f32_16x16x32_bf16(a1, b1, acc[1][1], 0, 0, 0);
  }

  const int rbase = kgr * 4;
#pragma unroll
  for (int nt = 0; nt < 2; ++nt) {
    int o = (wave * 2 + nt) * 16 + nlo;
    float bd = b_dc[o], ss = s2[o], tt = t2[o];
#pragma unroll
    for (int mt = 0; mt < 2; ++mt)
#pragma unroll
      for (int r = 0; r < 4; ++r) {
        int w = wq * 32 + mt * 16 + rbase + r;
        float v = acc[mt][nt][r] + bd;
        v = fmaxf(ss * v + tt, 0.f);
        dc[((size_t)((b * 128 + h) * 128 + w)) * 128 + o] = f2bf(v);
      }
  }
}

// ---------------------------------------------------------------------------
// K4: conv3 MFMA (M=32, N=128, K=128) + bn3a/relu + bn3b, then LDS transpose
// epilogue adding ident + final relu -> out NCHW fp32 (coalesced).
// grid (4,128,4); block 256 = 4 waves; A-frags direct from global dc (NHWC).
// ---------------------------------------------------------------------------
__global__ __launch_bounds__(256) void k_conv3(const u16* __restrict__ dc,
                                               const u16* __restrict__ w3b,
                                               const float* __restrict__ s3a, const float* __restrict__ t3a,
                                               const float* __restrict__ s3b, const float* __restrict__ t3b,
                                               const u16* __restrict__ identb,
                                               float* __restrict__ out) {
  __shared__ __align__(16) float T2[128 * 36];   // [o][pos], pitch 36
  const int tid = threadIdx.x;
  const int wq = blockIdx.x, h = blockIdx.y, b = blockIdx.z;
  const int wave = tid >> 6, lane = tid & 63;
  const int nlo = lane & 15, kgr = lane >> 4;

  const u16* abase = dc + ((size_t)((b * 128 + h) * 128) + wq * 32) * 128;
  float4v acc[2][2];
#pragma unroll
  for (int mt = 0; mt < 2; ++mt)
#pragma unroll
    for (int nt = 0; nt < 2; ++nt) acc[mt][nt] = (float4v)(0.f);

  const u16* b0p = &w3b[(((size_t)(wave * 2 + 0) * 4) * 64 + lane) * 8];
  const u16* b1p = &w3b[(((size_t)(wave * 2 + 1) * 4) * 64 + lane) * 8];
#pragma unroll
  for (int ks = 0; ks < 4; ++ks) {
    short8v a0 = *(const short8v*)(abase + (size_t)nlo * 128 + ks * 32 + kgr * 8);
    short8v a1 = *(const short8v*)(abase + (size_t)(nlo + 16) * 128 + ks * 32 + kgr * 8);
    short8v b0 = *(const short8v*)(b0p + ks * 512);
    short8v b1 = *(const short8v*)(b1p + ks * 512);
    acc[0][0] = __builtin_amdgcn_mfma_f32_16x16x32_bf16(a0, b0, acc[0][0], 0, 0, 0);
    acc[0][1] = __builtin_amdgcn_mfma_f32_16x16x32_bf16(a0, b1, acc[0][1], 0, 0, 0);
    acc[1][0] = __builtin_amdgcn_mfma_f32_16x16x32_bf16(a1, b0, acc[1][0], 0, 0, 0);
    acc[1][1] = __builtin_amdgcn_mfma_f32_16x16x32_bf16(a1, b1, acc[1][1], 0, 0, 0);
  }

  const int rbase = kgr * 4;
#pragma unroll
  for (int nt = 0; nt < 2; ++nt) {
    int o = (wave * 2 + nt) * 16 + nlo;
    float sa = s3a[o], ta = t3a[o], sb = s3b[o], tb = t3b[o];
#pragma unroll
    for (int mt = 0; mt < 2; ++mt)
#pragma unroll
      for (int r = 0; r < 4; ++r) {
        float v = acc[mt][nt][r];
        v = fmaxf(sa * v + ta, 0.f);
        v = sb * v + tb;
        T2[o * 36 + mt * 16 + rbase + r] = v;
      }
  }
  __syncthreads();

  {
    int o = tid >> 1, half = tid & 1;
    size_t g = ((size_t)((b * 128 + o) * 128 + h)) * 128 + wq * 32 + half * 16;
    const float* trow = &T2[o * 36 + half * 16];
    uint4 iv0 = *(const uint4*)&identb[g];
    uint4 iv1 = *(const uint4*)&identb[g + 8];
    u32 iw[8] = {iv0.x, iv0.y, iv0.z, iv0.w, iv1.x, iv1.y, iv1.z, iv1.w};
    float4 ov[4];
#pragma unroll
    for (int q = 0; q < 4; ++q) {
      float r0 = trow[q * 4 + 0] + bflo(iw[q * 2]);
      float r1 = trow[q * 4 + 1] + bfhi(iw[q * 2]);
      float r2 = trow[q * 4 + 2] + bflo(iw[q * 2 + 1]);
      float r3 = trow[q * 4 + 3] + bfhi(iw[q * 2 + 1]);
      ov[q] = make_float4(fmaxf(r0, 0.f), fmaxf(r1, 0.f), fmaxf(r2, 0.f), fmaxf(r3, 0.f));
    }
#pragma unroll
    for (int q = 0; q < 4; ++q)
      *(float4*)&out[g + q * 4] = ov[q];
  }
}

// ---------------------------------------------------------------------------
extern "C" void kernel_launch(void* const* d_in, const int* in_sizes, int n_in,
                              void* d_out, int out_size, void* d_ws, size_t ws_size,
                              hipStream_t stream) {
  const float* x     = (const float*)d_in[0];
  const float* w1    = (const float*)d_in[1];
  const float* s1a   = (const float*)d_in[2];
  const float* t1a   = (const float*)d_in[3];
  const float* s1b   = (const float*)d_in[4];
  const float* t1b   = (const float*)d_in[5];
  const float* w_off = (const float*)d_in[6];
  const float* b_off = (const float*)d_in[7];
  const float* w_dc  = (const float*)d_in[8];
  const float* b_dc  = (const float*)d_in[9];
  const float* s2    = (const float*)d_in[10];
  const float* t2    = (const float*)d_in[11];
  const float* w3    = (const float*)d_in[12];
  const float* s3a   = (const float*)d_in[13];
  const float* t3a   = (const float*)d_in[14];
  const float* s3b   = (const float*)d_in[15];
  const float* t3b   = (const float*)d_in[16];
  const float* w_ds  = (const float*)d_in[17];
  const float* b_ds  = (const float*)d_in[18];
  const float* sd    = (const float*)d_in[19];
  const float* td    = (const float*)d_in[20];

  // Workspace layout (57,942,016 B; previous 57,999,360 fit).
  char* ws = (char*)d_ws;
  u16*   wTb    = (u16*)(ws + 0);            //   294,912 B
  u16*   wB1    = (u16*)(ws + 294912);       //   131,072 B
  u16*   w3b    = (u16*)(ws + 425984);       //    32,768 B
  u16*   woffb  = (u16*)(ws + 458752);       //    73,728 B
  float* offs   = (float*)(ws + 532480);     // 7,077,888 B
  u16*   out1   = (u16*)(ws + 7610368);      // 16,777,216 B  NHWC bf16
  u16*   dc     = (u16*)(ws + 24387584);     // 16,777,216 B  NHWC bf16
  u16*   identb = (u16*)(ws + 41164800);     // 16,777,216 B  NCHW bf16

  k_init  <<<1040, 256, 0, stream>>>(w_dc, w1, w_ds, w3, w_off, wTb, wB1, w3b, woffb);
  k_fused1<<<dim3(4, 128, 4), 256, 0, stream>>>(x, wB1, s1a, t1a, s1b, t1b, b_ds, sd, td, out1, identb);
  k_off2  <<<dim3(4, 128, 4), 256, 0, stream>>>(out1, woffb, b_off, offs);
  k_dcn   <<<dim3(4, 128, 4), 256, 0, stream>>>(out1, offs, wTb, b_dc, s2, t2, dc);
  k_conv3 <<<dim3(4, 128, 4), 256, 0, stream>>>(dc, w3b, s3a, t3a, s3b, t3b, identb, (float*)d_out);
}

// Round 6
// 343.993 us; speedup vs baseline: 4.9109x; 1.1354x over previous
//
#include <hip/hip_runtime.h>
#include <hip/hip_bf16.h>

#define HW 16384   // 128*128

typedef unsigned short u16;
typedef unsigned int   u32;
typedef __attribute__((ext_vector_type(8))) short short8v;
typedef __attribute__((ext_vector_type(4))) float float4v;

__device__ __forceinline__ float b2f(u16 v) { return __uint_as_float((u32)v << 16); }
__device__ __forceinline__ u16 f2bf(float f) {
  u32 u = __float_as_uint(f);
  u32 r = (u + 0x7fffu + ((u >> 16) & 1u)) >> 16;
  return (u16)r;
}
__device__ __forceinline__ float bflo(u32 u) { return __uint_as_float(u << 16); }
__device__ __forceinline__ float bfhi(u32 u) { return __uint_as_float(u & 0xffff0000u); }
__device__ __forceinline__ u32 pk2(float a, float b) { return ((u32)f2bf(b) << 16) | (u32)f2bf(a); }

// ---------------------------------------------------------------------------
// K0: swizzle ALL weights into MFMA-B fragment order (bf16).
//  B-frag layout: buf[((ntile*KS + ks)*64 + lane)*8 + j]
//  with o = ntile*16 + (lane&15), k = ks*32 + (lane>>4)*8 + j.
// ---------------------------------------------------------------------------
__global__ __launch_bounds__(256) void k_init(const float* __restrict__ w_dc,
                                              const float* __restrict__ w1,
                                              const float* __restrict__ w_ds,
                                              const float* __restrict__ w3,
                                              const float* __restrict__ w_off,
                                              u16* __restrict__ wTb, u16* __restrict__ wB1,
                                              u16* __restrict__ w3b, u16* __restrict__ woffb) {
  int idx = blockIdx.x * 256 + threadIdx.x;
  if (idx < 147456) {
    int ntile = idx / 18432, r = idx % 18432;
    int ks = r / 512, r2 = r % 512;
    int lane = r2 / 8, j = r2 % 8;
    int o = ntile * 16 + (lane & 15);
    int k = ks * 32 + ((lane >> 4) * 8) + j;
    int tap = k >> 7, ci = k & 127;
    wTb[idx] = f2bf(w_dc[(o * 128 + ci) * 9 + tap]);
  }
  int i1 = idx - 147456;
  if (i1 >= 0 && i1 < 65536) {
    int ntile = i1 / 4096, r = i1 % 4096;
    int ks = r / 512, r2 = r % 512;
    int lane = r2 / 8, j = r2 % 8;
    int o = ntile * 16 + (lane & 15);
    int c = ks * 32 + ((lane >> 4) * 8) + j;
    float v = (ntile < 8) ? w1[o * 256 + c] : w_ds[(o - 128) * 256 + c];
    wB1[i1] = f2bf(v);
  }
  int i2 = idx - 212992;
  if (i2 >= 0 && i2 < 16384) {
    int ntile = i2 / 2048, r = i2 % 2048;
    int ks = r / 512, r2 = r % 512;
    int lane = r2 / 8, j = r2 % 8;
    int o = ntile * 16 + (lane & 15);
    int c = ks * 32 + ((lane >> 4) * 8) + j;
    w3b[i2] = f2bf(w3[o * 128 + c]);
  }
  int i3 = idx - 229376;
  if (i3 >= 0 && i3 < 36864) {
    int ntile = i3 / 18432, r = i3 % 18432;
    int ks = r / 512, r2 = r % 512;
    int lane = r2 / 8, j = r2 % 8;
    int oc = ntile * 16 + (lane & 15);
    int k = ks * 32 + ((lane >> 4) * 8) + j;
    int tap = k >> 7, c = k & 127;
    woffb[i3] = (oc < 27) ? f2bf(w_off[oc * 1152 + c * 9 + tap]) : (u16)0;
  }
}

// ---------------------------------------------------------------------------
// K1: fused conv1+downsample MFMA GEMM. M=32 pos, N=256, K=256.
// grid (4,128,4); block 256 = 4 waves.
// ---------------------------------------------------------------------------
__global__ __launch_bounds__(256) void k_fused1(const float* __restrict__ x,
                                                const u16* __restrict__ wB1,
                                                const float* __restrict__ s1a, const float* __restrict__ t1a,
                                                const float* __restrict__ s1b, const float* __restrict__ t1b,
                                                const float* __restrict__ b_ds,
                                                const float* __restrict__ sd, const float* __restrict__ td,
                                                u16* __restrict__ out1,      // [b][h][w][o]
                                                u16* __restrict__ identb)    // [b][o][h][w]
{
  __shared__ __align__(16) u16 xA[32 * 264];   // [pos][c] bf16, pitch 264
  __shared__ __align__(16) u16 T1[128 * 34];   // [o][pos] transpose buffer
  const int tid = threadIdx.x;
  const int wq = blockIdx.x, h = blockIdx.y, b = blockIdx.z;
  const int wave = tid >> 6, lane = tid & 63;

  {
    const float* xb = x + (size_t)b * 256 * HW + h * 128 + wq * 32;
    int cr = tid >> 3, wg = tid & 7;
#pragma unroll
    for (int i = 0; i < 8; ++i) {
      int c = i * 32 + cr;
      float4 v = *(const float4*)&xb[(size_t)c * HW + wg * 4];
      int p0 = wg * 4;
      xA[(p0 + 0) * 264 + c] = f2bf(v.x);
      xA[(p0 + 1) * 264 + c] = f2bf(v.y);
      xA[(p0 + 2) * 264 + c] = f2bf(v.z);
      xA[(p0 + 3) * 264 + c] = f2bf(v.w);
    }
  }
  __syncthreads();

  const int nlo = lane & 15, kgr = lane >> 4;
  float4v acc[2][4];
#pragma unroll
  for (int mt = 0; mt < 2; ++mt)
#pragma unroll
    for (int nt = 0; nt < 4; ++nt) acc[mt][nt] = (float4v)(0.f);

  const u16* a0p = &xA[nlo * 264 + kgr * 8];
  const u16* a1p = &xA[(nlo + 16) * 264 + kgr * 8];
  const u16* bp = &wB1[(((size_t)(wave * 4) * 8) * 64 + lane) * 8];

#pragma unroll
  for (int ks = 0; ks < 8; ++ks) {
    short8v a0 = *(const short8v*)(a0p + ks * 32);
    short8v a1 = *(const short8v*)(a1p + ks * 32);
#pragma unroll
    for (int nt = 0; nt < 4; ++nt) {
      short8v bv = *(const short8v*)(bp + nt * 4096 + ks * 512);
      acc[0][nt] = __builtin_amdgcn_mfma_f32_16x16x32_bf16(a0, bv, acc[0][nt], 0, 0, 0);
      acc[1][nt] = __builtin_amdgcn_mfma_f32_16x16x32_bf16(a1, bv, acc[1][nt], 0, 0, 0);
    }
  }

  const int rbase = kgr * 4;
  if (wave < 2) {
#pragma unroll
    for (int nt = 0; nt < 4; ++nt) {
      int o = (wave * 4 + nt) * 16 + nlo;
      float sa = s1a[o], ta = t1a[o], sb = s1b[o], tb = t1b[o];
#pragma unroll
      for (int mt = 0; mt < 2; ++mt)
#pragma unroll
        for (int r = 0; r < 4; ++r) {
          float v = acc[mt][nt][r];
          v = fmaxf(sa * v + ta, 0.f);
          v = fmaxf(sb * v + tb, 0.f);
          int pos = mt * 16 + rbase + r;
          out1[((size_t)((b * 128 + h) * 128 + wq * 32 + pos)) * 128 + o] = f2bf(v);
        }
    }
  } else {
#pragma unroll
    for (int nt = 0; nt < 4; ++nt) {
      int og = (wave * 4 + nt) * 16 + nlo - 128;
      float sv = sd[og], tv = td[og], bv = b_ds[og];
#pragma unroll
      for (int mt = 0; mt < 2; ++mt)
#pragma unroll
        for (int r = 0; r < 4; ++r) {
          float v = sv * (acc[mt][nt][r] + bv) + tv;
          T1[og * 34 + mt * 16 + rbase + r] = f2bf(v);
        }
    }
  }
  __syncthreads();

  {
    int o = tid >> 1, half = tid & 1;
    const u16* src = &T1[o * 34 + half * 16];
    u32 bb[8];
#pragma unroll
    for (int i = 0; i < 8; ++i) bb[i] = *(const u32*)(src + i * 2);
    size_t g = ((size_t)((b * 128 + o) * 128 + h)) * 128 + wq * 32 + half * 16;
    *(uint4*)&identb[g] = make_uint4(bb[0], bb[1], bb[2], bb[3]);
    *(uint4*)&identb[g + 8] = make_uint4(bb[4], bb[5], bb[6], bb[7]);
  }
}

// ---------------------------------------------------------------------------
// K2: offset conv as im2col MFMA. M=32 pos, N=32 (27 + pad), K=1152.
// ---------------------------------------------------------------------------
__global__ __launch_bounds__(256) void k_off2(const u16* __restrict__ out1,
                                              const u16* __restrict__ woffb,
                                              const float* __restrict__ b_off,
                                              float* __restrict__ offs) {
  __shared__ __align__(16) u16 Alds[32 * 1160];
  const int tid = threadIdx.x;
  const int wq = blockIdx.x, h = blockIdx.y, b = blockIdx.z;
  const int wave = tid >> 6, lane = tid & 63;
  const u16* base = out1 + (size_t)b * HW * 128;

  for (int job = wave; job < 288; job += 4) {
    int pos = job / 9, tap = job % 9;
    int w = wq * 32 + pos;
    int yy = h + tap / 3 - 1, xx = w + tap % 3 - 1;
    int c = lane * 2;
    u32 v = 0;
    if (yy >= 0 && yy < 128 && xx >= 0 && xx < 128)
      v = *(const u32*)&base[(size_t)(yy * 128 + xx) * 128 + c];
    *(u32*)&Alds[pos * 1160 + tap * 128 + c] = v;
  }
  __syncthreads();

  const int nlo = lane & 15, kgr = lane >> 4;
  const int mt = wave >> 1, nt = wave & 1;
  float4v acc = (float4v)(0.f);
  const u16* ap = &Alds[(mt * 16 + nlo) * 1160 + kgr * 8];
  const u16* bp = &woffb[(((size_t)nt * 36) * 64 + lane) * 8];
  for (int ks = 0; ks < 36; ++ks) {
    short8v a = *(const short8v*)(ap + ks * 32);
    short8v bv = *(const short8v*)(bp + ks * 512);
    acc = __builtin_amdgcn_mfma_f32_16x16x32_bf16(a, bv, acc, 0, 0, 0);
  }

  int oc = nt * 16 + nlo;
  if (oc < 27) {
    float bo = b_off[oc];
#pragma unroll
    for (int r = 0; r < 4; ++r) {
      int w = wq * 32 + mt * 16 + kgr * 4 + r;
      float v = acc[r] + bo;
      if (oc >= 18) v = 1.f / (1.f + __expf(-v));
      offs[(size_t)((b * 128 + h) * 128 + w) * 27 + oc] = v;
    }
  }
}

// ---------------------------------------------------------------------------
// K3: DCNv2 sampling + MFMA GEMM (M=32,N=128,K=1152) + bn2/relu
//     + FUSED conv3 (M=32,N=128,K=128) + bn3a/relu + bn3b + ident + relu
//     -> out NCHW fp32.  grid (4,128,4); block 256 = 4 waves.
// Phase 1a: 288 jobs' uniform scalars (clamped base addr, steps, 4 weights)
//           computed one-job-per-thread into jobtab (kills 64x redundancy).
// Phase 1b: per-lane gather+blend -> Alds A-tile.
// Phase 2:  MFMA K=1152 vs wTb.
// Phase 3:  bn2/relu -> P[pos][o] bf16 (aliases Alds) -> MFMA K=128 vs w3b.
// Phase 4:  bn3 chain -> T2 (aliases Alds) -> transpose + ident + relu -> out.
// ---------------------------------------------------------------------------
__global__ __launch_bounds__(256) void k_dcn(const u16* __restrict__ out1,
                                             const float* __restrict__ offs,
                                             const u16* __restrict__ wTb,
                                             const u16* __restrict__ w3b,
                                             const float* __restrict__ b_dc,
                                             const float* __restrict__ s2, const float* __restrict__ t2,
                                             const float* __restrict__ s3a, const float* __restrict__ t3a,
                                             const float* __restrict__ s3b, const float* __restrict__ t3b,
                                             const u16* __restrict__ identb,
                                             float* __restrict__ out) {
  __shared__ __align__(16) u16 Alds[32 * 1160];   // 74,240 B (aliased later)
  __shared__ __align__(16) u32 jobtab[288 * 6];   //  6,912 B
  u16*   P  = (u16*)Alds;                          // [pos][o] pitch 136, 8,704 B
  float* T2 = (float*)((char*)Alds + 8704);        // [o][pos] pitch 36, 18,432 B

  const int tid = threadIdx.x;
  const int wq = blockIdx.x, h = blockIdx.y, b = blockIdx.z;
  const int wave = tid >> 6, lane = tid & 63;
  const u16* base = out1 + (size_t)b * HW * 128;

  // ---- Phase 1a: per-job uniform scalars (one job per thread) ----
  for (int j = tid; j < 288; j += 256) {
    int pos = j / 9, tap = j % 9;
    int w = wq * 32 + pos;
    const float* op = offs + ((size_t)((b * 128 + h) * 128) + w) * 27;
    float dy = op[tap], dxv = op[9 + tap], mk = op[18 + tap];
    float py = (float)(h - 1 + tap / 3) + dy;
    float px = (float)(w - 1 + tap % 3) + dxv;
    float fy = floorf(py), fx = floorf(px);
    int y0 = (int)fy, x0 = (int)fx;
    float wy = py - fy, wxf = px - fx;
    bool vy0 = (y0 >= 0) & (y0 < 128), vy1 = (y0 >= -1) & (y0 < 127);
    bool vx0 = (x0 >= 0) & (x0 < 128), vx1 = (x0 >= -1) & (x0 < 127);
    float w00 = (vy0 & vx0) ? (1.f - wy) * (1.f - wxf) * mk : 0.f;
    float w01 = (vy0 & vx1) ? (1.f - wy) * wxf * mk : 0.f;
    float w10 = (vy1 & vx0) ? wy * (1.f - wxf) * mk : 0.f;
    float w11 = (vy1 & vx1) ? wy * wxf * mk : 0.f;
    int y0c = min(max(y0, 0), 127), y1c = min(max(y0 + 1, 0), 127);
    int x0c = min(max(x0, 0), 127), x1c = min(max(x0 + 1, 0), 127);
    u32* jt = &jobtab[j * 6];
    jt[0] = (u32)((y0c * 128 + x0c) * 128);
    jt[1] = (u32)((x1c - x0c) * 128) | ((u32)((y1c - y0c) * 16384) << 16);
    ((float*)jt)[2] = w00; ((float*)jt)[3] = w01;
    ((float*)jt)[4] = w10; ((float*)jt)[5] = w11;
  }
  __syncthreads();

  // ---- Phase 1b: per-lane gather + blend ----
  for (int job = wave; job < 288; job += 4) {
    int pos = job / 9, tap = job % 9;
    const u32* jt = &jobtab[job * 6];
    u32 a00 = jt[0], st = jt[1];
    float w00 = ((const float*)jt)[2], w01 = ((const float*)jt)[3];
    float w10 = ((const float*)jt)[4], w11 = ((const float*)jt)[5];
    int dxs = (int)(st & 0xffffu), dys = (int)(st >> 16);
    int c = lane * 2;
    const u16* p00 = base + a00 + c;
    u32 v00 = *(const u32*)p00;
    u32 v01 = *(const u32*)(p00 + dxs);
    u32 v10 = *(const u32*)(p00 + dys);
    u32 v11 = *(const u32*)(p00 + dys + dxs);
    float lo = w00 * bflo(v00) + w01 * bflo(v01) + w10 * bflo(v10) + w11 * bflo(v11);
    float hi = w00 * bfhi(v00) + w01 * bfhi(v01) + w10 * bfhi(v10) + w11 * bfhi(v11);
    *(u32*)&Alds[pos * 1160 + tap * 128 + c] = pk2(lo, hi);
  }
  __syncthreads();

  // ---- Phase 2: DCN MFMA (K=1152) ----
  const int nlo = lane & 15, kgr = lane >> 4;
  float4v acc[2][2];
#pragma unroll
  for (int mt = 0; mt < 2; ++mt)
#pragma unroll
    for (int nt = 0; nt < 2; ++nt) acc[mt][nt] = (float4v)(0.f);

  {
    const u16* a_base0 = &Alds[nlo * 1160 + kgr * 8];
    const u16* a_base1 = &Alds[(nlo + 16) * 1160 + kgr * 8];
    const u16* b_base0 = &wTb[(((size_t)(wave * 2 + 0) * 36) * 64 + lane) * 8];
    const u16* b_base1 = &wTb[(((size_t)(wave * 2 + 1) * 36) * 64 + lane) * 8];
    for (int ks = 0; ks < 36; ++ks) {
      short8v a0 = *(const short8v*)(a_base0 + ks * 32);
      short8v a1 = *(const short8v*)(a_base1 + ks * 32);
      short8v b0 = *(const short8v*)(b_base0 + (size_t)ks * 512);
      short8v b1 = *(const short8v*)(b_base1 + (size_t)ks * 512);
      acc[0][0] = __builtin_amdgcn_mfma_f32_16x16x32_bf16(a0, b0, acc[0][0], 0, 0, 0);
      acc[0][1] = __builtin_amdgcn_mfma_f32_16x16x32_bf16(a0, b1, acc[0][1], 0, 0, 0);
      acc[1][0] = __builtin_amdgcn_mfma_f32_16x16x32_bf16(a1, b0, acc[1][0], 0, 0, 0);
      acc[1][1] = __builtin_amdgcn_mfma_f32_16x16x32_bf16(a1, b1, acc[1][1], 0, 0, 0);
    }
  }
  __syncthreads();   // all waves done reading Alds before P overwrites it

  // ---- Phase 3: bn2 + relu -> P[pos][o] bf16 ----
  const int rbase = kgr * 4;
#pragma unroll
  for (int nt = 0; nt < 2; ++nt) {
    int o = (wave * 2 + nt) * 16 + nlo;
    float bd = b_dc[o], ss = s2[o], tt = t2[o];
#pragma unroll
    for (int mt = 0; mt < 2; ++mt)
#pragma unroll
      for (int r = 0; r < 4; ++r) {
        float v = acc[mt][nt][r] + bd;
        v = fmaxf(ss * v + tt, 0.f);
        P[(mt * 16 + rbase + r) * 136 + o] = f2bf(v);
      }
  }
  __syncthreads();

  // conv3 MFMA (K=128)
  float4v acc2[2][2];
#pragma unroll
  for (int mt = 0; mt < 2; ++mt)
#pragma unroll
    for (int nt = 0; nt < 2; ++nt) acc2[mt][nt] = (float4v)(0.f);
  {
    const u16* b0p = &w3b[(((size_t)(wave * 2 + 0) * 4) * 64 + lane) * 8];
    const u16* b1p = &w3b[(((size_t)(wave * 2 + 1) * 4) * 64 + lane) * 8];
#pragma unroll
    for (int ks = 0; ks < 4; ++ks) {
      short8v a0 = *(const short8v*)&P[nlo * 136 + ks * 32 + kgr * 8];
      short8v a1 = *(const short8v*)&P[(nlo + 16) * 136 + ks * 32 + kgr * 8];
      short8v b0 = *(const short8v*)(b0p + ks * 512);
      short8v b1 = *(const short8v*)(b1p + ks * 512);
      acc2[0][0] = __builtin_amdgcn_mfma_f32_16x16x32_bf16(a0, b0, acc2[0][0], 0, 0, 0);
      acc2[0][1] = __builtin_amdgcn_mfma_f32_16x16x32_bf16(a0, b1, acc2[0][1], 0, 0, 0);
      acc2[1][0] = __builtin_amdgcn_mfma_f32_16x16x32_bf16(a1, b0, acc2[1][0], 0, 0, 0);
      acc2[1][1] = __builtin_amdgcn_mfma_f32_16x16x32_bf16(a1, b1, acc2[1][1], 0, 0, 0);
    }
  }

  // ---- Phase 4: bn3 chain -> T2 -> transpose + ident + relu -> out ----
#pragma unroll
  for (int nt = 0; nt < 2; ++nt) {
    int o = (wave * 2 + nt) * 16 + nlo;
    float sa = s3a[o], ta = t3a[o], sb = s3b[o], tb = t3b[o];
#pragma unroll
    for (int mt = 0; mt < 2; ++mt)
#pragma unroll
      for (int r = 0; r < 4; ++r) {
        float v = acc2[mt][nt][r];
        v = fmaxf(sa * v + ta, 0.f);
        v = sb * v + tb;
        T2[o * 36 + mt * 16 + rbase + r] = v;
      }
  }
  __syncthreads();

  {
    int o = tid >> 1, half = tid & 1;
    size_t g = ((size_t)((b * 128 + o) * 128 + h)) * 128 + wq * 32 + half * 16;
    const float* trow = &T2[o * 36 + half * 16];
    uint4 iv0 = *(const uint4*)&identb[g];
    uint4 iv1 = *(const uint4*)&identb[g + 8];
    u32 iw[8] = {iv0.x, iv0.y, iv0.z, iv0.w, iv1.x, iv1.y, iv1.z, iv1.w};
    float4 ov[4];
#pragma unroll
    for (int q = 0; q < 4; ++q) {
      float r0 = trow[q * 4 + 0] + bflo(iw[q * 2]);
      float r1 = trow[q * 4 + 1] + bfhi(iw[q * 2]);
      float r2 = trow[q * 4 + 2] + bflo(iw[q * 2 + 1]);
      float r3 = trow[q * 4 + 3] + bfhi(iw[q * 2 + 1]);
      ov[q] = make_float4(fmaxf(r0, 0.f), fmaxf(r1, 0.f), fmaxf(r2, 0.f), fmaxf(r3, 0.f));
    }
#pragma unroll
    for (int q = 0; q < 4; ++q)
      *(float4*)&out[g + q * 4] = ov[q];
  }
}

// ---------------------------------------------------------------------------
extern "C" void kernel_launch(void* const* d_in, const int* in_sizes, int n_in,
                              void* d_out, int out_size, void* d_ws, size_t ws_size,
                              hipStream_t stream) {
  const float* x     = (const float*)d_in[0];
  const float* w1    = (const float*)d_in[1];
  const float* s1a   = (const float*)d_in[2];
  const float* t1a   = (const float*)d_in[3];
  const float* s1b   = (const float*)d_in[4];
  const float* t1b   = (const float*)d_in[5];
  const float* w_off = (const float*)d_in[6];
  const float* b_off = (const float*)d_in[7];
  const float* w_dc  = (const float*)d_in[8];
  const float* b_dc  = (const float*)d_in[9];
  const float* s2    = (const float*)d_in[10];
  const float* t2    = (const float*)d_in[11];
  const float* w3    = (const float*)d_in[12];
  const float* s3a   = (const float*)d_in[13];
  const float* t3a   = (const float*)d_in[14];
  const float* s3b   = (const float*)d_in[15];
  const float* t3b   = (const float*)d_in[16];
  const float* w_ds  = (const float*)d_in[17];
  const float* b_ds  = (const float*)d_in[18];
  const float* sd    = (const float*)d_in[19];
  const float* td    = (const float*)d_in[20];

  char* ws = (char*)d_ws;
  u16*   wTb    = (u16*)(ws + 0);            //   294,912 B
  u16*   wB1    = (u16*)(ws + 294912);       //   131,072 B
  u16*   w3b    = (u16*)(ws + 425984);       //    32,768 B
  u16*   woffb  = (u16*)(ws + 458752);       //    73,728 B
  float* offs   = (float*)(ws + 532480);     // 7,077,888 B
  u16*   out1   = (u16*)(ws + 7610368);      // 16,777,216 B  NHWC bf16
  u16*   identb = (u16*)(ws + 24387584);     // 16,777,216 B  NCHW bf16

  k_init  <<<1040, 256, 0, stream>>>(w_dc, w1, w_ds, w3, w_off, wTb, wB1, w3b, woffb);
  k_fused1<<<dim3(4, 128, 4), 256, 0, stream>>>(x, wB1, s1a, t1a, s1b, t1b, b_ds, sd, td, out1, identb);
  k_off2  <<<dim3(4, 128, 4), 256, 0, stream>>>(out1, woffb, b_off, offs);
  k_dcn   <<<dim3(4, 128, 4), 256, 0, stream>>>(out1, offs, wTb, w3b, b_dc, s2, t2,
                                                s3a, t3a, s3b, t3b, identb, (float*)d_out);
}

// Round 7
// 313.752 us; speedup vs baseline: 5.3842x; 1.0964x over previous
//
#include <hip/hip_runtime.h>
#include <hip/hip_bf16.h>

#define HW 16384   // 128*128

typedef unsigned short u16;
typedef unsigned int   u32;
typedef __attribute__((ext_vector_type(8))) short short8v;
typedef __attribute__((ext_vector_type(4))) float float4v;

__device__ __forceinline__ float b2f(u16 v) { return __uint_as_float((u32)v << 16); }
__device__ __forceinline__ u16 f2bf(float f) {   // RNE (cold paths)
  u32 u = __float_as_uint(f);
  u32 r = (u + 0x7fffu + ((u >> 16) & 1u)) >> 16;
  return (u16)r;
}
__device__ __forceinline__ float bflo(u32 u) { return __uint_as_float(u << 16); }
__device__ __forceinline__ float bfhi(u32 u) { return __uint_as_float(u & 0xffff0000u); }
// 1-instruction truncating pack: (hi16(b)<<16)|hi16(a)  [v_perm_b32]
__device__ __forceinline__ u32 pkt(float a, float b) {
  return __builtin_amdgcn_perm(__float_as_uint(b), __float_as_uint(a), 0x07060302u);
}
__device__ __forceinline__ u16 bft(float v) { return (u16)(__float_as_uint(v) >> 16); }  // trunc

// ---------------------------------------------------------------------------
// K0: swizzle ALL weights into MFMA-B fragment order (bf16, RNE).
//  B-frag layout: buf[((ntile*KS + ks)*64 + lane)*8 + j]
//  with o = ntile*16 + (lane&15), k = ks*32 + (lane>>4)*8 + j.
// ---------------------------------------------------------------------------
__global__ __launch_bounds__(256) void k_init(const float* __restrict__ w_dc,
                                              const float* __restrict__ w1,
                                              const float* __restrict__ w_ds,
                                              const float* __restrict__ w3,
                                              const float* __restrict__ w_off,
                                              u16* __restrict__ wTb, u16* __restrict__ wB1,
                                              u16* __restrict__ w3b, u16* __restrict__ woffb) {
  int idx = blockIdx.x * 256 + threadIdx.x;
  if (idx < 147456) {
    int ntile = idx / 18432, r = idx % 18432;
    int ks = r / 512, r2 = r % 512;
    int lane = r2 / 8, j = r2 % 8;
    int o = ntile * 16 + (lane & 15);
    int k = ks * 32 + ((lane >> 4) * 8) + j;
    int tap = k >> 7, ci = k & 127;
    wTb[idx] = f2bf(w_dc[(o * 128 + ci) * 9 + tap]);
  }
  int i1 = idx - 147456;
  if (i1 >= 0 && i1 < 65536) {
    int ntile = i1 / 4096, r = i1 % 4096;
    int ks = r / 512, r2 = r % 512;
    int lane = r2 / 8, j = r2 % 8;
    int o = ntile * 16 + (lane & 15);
    int c = ks * 32 + ((lane >> 4) * 8) + j;
    float v = (ntile < 8) ? w1[o * 256 + c] : w_ds[(o - 128) * 256 + c];
    wB1[i1] = f2bf(v);
  }
  int i2 = idx - 212992;
  if (i2 >= 0 && i2 < 16384) {
    int ntile = i2 / 2048, r = i2 % 2048;
    int ks = r / 512, r2 = r % 512;
    int lane = r2 / 8, j = r2 % 8;
    int o = ntile * 16 + (lane & 15);
    int c = ks * 32 + ((lane >> 4) * 8) + j;
    w3b[i2] = f2bf(w3[o * 128 + c]);
  }
  int i3 = idx - 229376;
  if (i3 >= 0 && i3 < 36864) {
    int ntile = i3 / 18432, r = i3 % 18432;
    int ks = r / 512, r2 = r % 512;
    int lane = r2 / 8, j = r2 % 8;
    int oc = ntile * 16 + (lane & 15);
    int k = ks * 32 + ((lane >> 4) * 8) + j;
    int tap = k >> 7, c = k & 127;
    woffb[i3] = (oc < 27) ? f2bf(w_off[oc * 1152 + c * 9 + tap]) : (u16)0;
  }
}

// ---------------------------------------------------------------------------
// K1: fused conv1+downsample MFMA GEMM. M=32 pos, N=256, K=256.
// grid (4,128,4); block 256 = 4 waves. xA pitch 266 u16 (bank-clean).
// Staging packs row-pairs (c, c+1) via pkt -> single ds_write_b32.
// ---------------------------------------------------------------------------
__global__ __launch_bounds__(256) void k_fused1(const float* __restrict__ x,
                                                const u16* __restrict__ wB1,
                                                const float* __restrict__ s1a, const float* __restrict__ t1a,
                                                const float* __restrict__ s1b, const float* __restrict__ t1b,
                                                const float* __restrict__ b_ds,
                                                const float* __restrict__ sd, const float* __restrict__ td,
                                                u16* __restrict__ out1,      // [b][h][w][o]
                                                u16* __restrict__ identb)    // [b][o][h][w]
{
  __shared__ __align__(16) u16 xA[32 * 266];   // [pos][c] bf16, pitch 266
  __shared__ __align__(16) u16 T1[128 * 34];   // [o][pos] transpose buffer
  const int tid = threadIdx.x;
  const int wq = blockIdx.x, h = blockIdx.y, b = blockIdx.z;
  const int wave = tid >> 6, lane = tid & 63;

  {
    const float* xb = x + (size_t)b * 256 * HW + h * 128 + wq * 32;
    u32* dst = (u32*)xA;                 // u32 pitch 133 per pos row
    int cp = tid >> 3, wg = tid & 7;
#pragma unroll
    for (int i = 0; i < 4; ++i) {
      int cpair = i * 32 + cp;           // 0..127
      int c0 = cpair * 2;
      float4 va = *(const float4*)&xb[(size_t)c0 * HW + wg * 4];
      float4 vb = *(const float4*)&xb[(size_t)(c0 + 1) * HW + wg * 4];
      int p0 = wg * 4;
      dst[(p0 + 0) * 133 + cpair] = pkt(va.x, vb.x);
      dst[(p0 + 1) * 133 + cpair] = pkt(va.y, vb.y);
      dst[(p0 + 2) * 133 + cpair] = pkt(va.z, vb.z);
      dst[(p0 + 3) * 133 + cpair] = pkt(va.w, vb.w);
    }
  }
  __syncthreads();

  const int nlo = lane & 15, kgr = lane >> 4;
  float4v acc[2][4];
#pragma unroll
  for (int mt = 0; mt < 2; ++mt)
#pragma unroll
    for (int nt = 0; nt < 4; ++nt) acc[mt][nt] = (float4v)(0.f);

  const u16* a0p = &xA[nlo * 266 + kgr * 8];
  const u16* a1p = &xA[(nlo + 16) * 266 + kgr * 8];
  const u16* bp = &wB1[(((size_t)(wave * 4) * 8) * 64 + lane) * 8];

#pragma unroll
  for (int ks = 0; ks < 8; ++ks) {
    short8v a0 = *(const short8v*)(a0p + ks * 32);
    short8v a1 = *(const short8v*)(a1p + ks * 32);
#pragma unroll
    for (int nt = 0; nt < 4; ++nt) {
      short8v bv = *(const short8v*)(bp + nt * 4096 + ks * 512);
      acc[0][nt] = __builtin_amdgcn_mfma_f32_16x16x32_bf16(a0, bv, acc[0][nt], 0, 0, 0);
      acc[1][nt] = __builtin_amdgcn_mfma_f32_16x16x32_bf16(a1, bv, acc[1][nt], 0, 0, 0);
    }
  }

  const int rbase = kgr * 4;
  if (wave < 2) {
#pragma unroll
    for (int nt = 0; nt < 4; ++nt) {
      int o = (wave * 4 + nt) * 16 + nlo;
      float sa = s1a[o], ta = t1a[o], sb = s1b[o], tb = t1b[o];
#pragma unroll
      for (int mt = 0; mt < 2; ++mt)
#pragma unroll
        for (int r = 0; r < 4; ++r) {
          float v = acc[mt][nt][r];
          v = fmaxf(sa * v + ta, 0.f);
          v = fmaxf(sb * v + tb, 0.f);
          int pos = mt * 16 + rbase + r;
          out1[((size_t)((b * 128 + h) * 128 + wq * 32 + pos)) * 128 + o] = bft(v);
        }
    }
  } else {
#pragma unroll
    for (int nt = 0; nt < 4; ++nt) {
      int og = (wave * 4 + nt) * 16 + nlo - 128;
      float sv = sd[og], tv = td[og], bv = b_ds[og];
#pragma unroll
      for (int mt = 0; mt < 2; ++mt)
#pragma unroll
        for (int r = 0; r < 4; ++r) {
          float v = sv * (acc[mt][nt][r] + bv) + tv;
          T1[og * 34 + mt * 16 + rbase + r] = bft(v);
        }
    }
  }
  __syncthreads();

  {
    int o = tid >> 1, half = tid & 1;
    const u16* src = &T1[o * 34 + half * 16];
    u32 bb[8];
#pragma unroll
    for (int i = 0; i < 8; ++i) bb[i] = *(const u32*)(src + i * 2);
    size_t g = ((size_t)((b * 128 + o) * 128 + h)) * 128 + wq * 32 + half * 16;
    *(uint4*)&identb[g] = make_uint4(bb[0], bb[1], bb[2], bb[3]);
    *(uint4*)&identb[g + 8] = make_uint4(bb[4], bb[5], bb[6], bb[7]);
  }
}

// ---------------------------------------------------------------------------
// K2: MEGA-FUSED DCNv2: offset-conv MFMA + bilinear sampling + DCN MFMA
//     (M=16,N=128,K=1152) + bn2/relu + conv3 MFMA (K=128) + bn3 + ident + relu
//     -> out NCHW fp32.  grid (8,128,4); block 256 = 4 waves.
// LDS 42.4 KB -> 3 blocks/CU.
// ---------------------------------------------------------------------------
__global__ __launch_bounds__(256) void k_dcn(const u16* __restrict__ out1,
                                             const u16* __restrict__ wTb,
                                             const u16* __restrict__ w3b,
                                             const u16* __restrict__ woffb,
                                             const float* __restrict__ b_off,
                                             const float* __restrict__ b_dc,
                                             const float* __restrict__ s2, const float* __restrict__ t2,
                                             const float* __restrict__ s3a, const float* __restrict__ t3a,
                                             const float* __restrict__ s3b, const float* __restrict__ t3b,
                                             const u16* __restrict__ identb,
                                             float* __restrict__ out) {
  __shared__ __align__(16) u16 Alds[16 * 1162];   // 37,184 B (A-tile; later P/T2)
  __shared__ __align__(16) u32 jobtab[144 * 6];   //  3,456 B
  __shared__ __align__(16) float offl[16 * 27];   //  1,728 B
  u16*   P  = (u16*)Alds;                          // [pos][o] pitch 136: 4,352 B
  float* T2 = (float*)((char*)Alds + 8704);        // [o][pos] pitch 17: 8,704 B

  const int tid = threadIdx.x;
  const int wq = blockIdx.x, h = blockIdx.y, b = blockIdx.z;
  const int wave = tid >> 6, lane = tid & 63;
  const int nlo = lane & 15, kgr = lane >> 4;
  const u16* base = out1 + (size_t)b * HW * 128;

  // ---- Phase 0a: integer-tap gather for the offset conv ----
  for (int job = wave; job < 144; job += 4) {
    int pos = job / 9, tap = job % 9;
    int w = wq * 16 + pos;
    int yy = h + tap / 3 - 1, xx = w + tap % 3 - 1;
    int c = lane * 2;
    u32 v = 0;
    if (yy >= 0 && yy < 128 && xx >= 0 && xx < 128)
      v = *(const u32*)&base[(size_t)(yy * 128 + xx) * 128 + c];
    *(u32*)&Alds[pos * 1162 + tap * 128 + c] = v;
  }
  __syncthreads();

  // ---- Phase 0b: offset-conv MFMA (waves 0-1), N=16 each, K=1152 ----
  if (wave < 2) {
    float4v oacc = (float4v)(0.f);
    const u16* ap = &Alds[nlo * 1162 + kgr * 8];
    const u16* bp = &woffb[(((size_t)wave * 36) * 64 + lane) * 8];
    for (int ks = 0; ks < 36; ++ks) {
      short8v a = *(const short8v*)(ap + ks * 32);
      short8v bv = *(const short8v*)(bp + (size_t)ks * 512);
      oacc = __builtin_amdgcn_mfma_f32_16x16x32_bf16(a, bv, oacc, 0, 0, 0);
    }
    int oc = wave * 16 + nlo;
    if (oc < 27) {
      float bo = b_off[oc];
#pragma unroll
      for (int r = 0; r < 4; ++r) {
        int pos = kgr * 4 + r;
        float v = oacc[r] + bo;
        if (oc >= 18) v = 1.f / (1.f + __expf(-v));
        offl[pos * 27 + oc] = v;
      }
    }
  }
  __syncthreads();

  // ---- Phase 1a: per-job uniform scalars into jobtab ----
  if (tid < 144) {
    int pos = tid / 9, tap = tid % 9;
    int w = wq * 16 + pos;
    float dy = offl[pos * 27 + tap];
    float dxv = offl[pos * 27 + 9 + tap];
    float mk = offl[pos * 27 + 18 + tap];
    float py = (float)(h - 1 + tap / 3) + dy;
    float px = (float)(w - 1 + tap % 3) + dxv;
    float fy = floorf(py), fx = floorf(px);
    int y0 = (int)fy, x0 = (int)fx;
    float wy = py - fy, wxf = px - fx;
    bool vy0 = (y0 >= 0) & (y0 < 128), vy1 = (y0 >= -1) & (y0 < 127);
    bool vx0 = (x0 >= 0) & (x0 < 128), vx1 = (x0 >= -1) & (x0 < 127);
    float w00 = (vy0 & vx0) ? (1.f - wy) * (1.f - wxf) * mk : 0.f;
    float w01 = (vy0 & vx1) ? (1.f - wy) * wxf * mk : 0.f;
    float w10 = (vy1 & vx0) ? wy * (1.f - wxf) * mk : 0.f;
    float w11 = (vy1 & vx1) ? wy * wxf * mk : 0.f;
    int y0c = min(max(y0, 0), 127), y1c = min(max(y0 + 1, 0), 127);
    int x0c = min(max(x0, 0), 127), x1c = min(max(x0 + 1, 0), 127);
    u32* jt = &jobtab[tid * 6];
    jt[0] = (u32)((y0c * 128 + x0c) * 128);
    jt[1] = (u32)((x1c - x0c) * 128) | ((u32)((y1c - y0c) * 16384) << 16);
    ((float*)jt)[2] = w00; ((float*)jt)[3] = w01;
    ((float*)jt)[4] = w10; ((float*)jt)[5] = w11;
  }
  __syncthreads();

  // ---- Phase 1b: bilinear gather + blend, 2-job unroll ----
  {
    const int c = lane * 2;
#pragma unroll 2
    for (int i = 0; i < 18; ++i) {
      int jA = wave + 8 * i, jB = jA + 4;
      const u32* jtA = &jobtab[jA * 6];
      const u32* jtB = &jobtab[jB * 6];
      u32 aA = jtA[0], stA = jtA[1];
      u32 aB = jtB[0], stB = jtB[1];
      const u16* pA = base + aA + c;
      const u16* pB = base + aB + c;
      int dxA = (int)(stA & 0xffffu), dyA = (int)(stA >> 16);
      int dxB = (int)(stB & 0xffffu), dyB = (int)(stB >> 16);
      u32 vA00 = *(const u32*)pA;
      u32 vA01 = *(const u32*)(pA + dxA);
      u32 vA10 = *(const u32*)(pA + dyA);
      u32 vA11 = *(const u32*)(pA + dyA + dxA);
      u32 vB00 = *(const u32*)pB;
      u32 vB01 = *(const u32*)(pB + dxB);
      u32 vB10 = *(const u32*)(pB + dyB);
      u32 vB11 = *(const u32*)(pB + dyB + dxB);
      float wA00 = ((const float*)jtA)[2], wA01 = ((const float*)jtA)[3];
      float wA10 = ((const float*)jtA)[4], wA11 = ((const float*)jtA)[5];
      float wB00 = ((const float*)jtB)[2], wB01 = ((const float*)jtB)[3];
      float wB10 = ((const float*)jtB)[4], wB11 = ((const float*)jtB)[5];
      float loA = wA00 * bflo(vA00) + wA01 * bflo(vA01) + wA10 * bflo(vA10) + wA11 * bflo(vA11);
      float hiA = wA00 * bfhi(vA00) + wA01 * bfhi(vA01) + wA10 * bfhi(vA10) + wA11 * bfhi(vA11);
      float loB = wB00 * bflo(vB00) + wB01 * bflo(vB01) + wB10 * bflo(vB10) + wB11 * bflo(vB11);
      float hiB = wB00 * bfhi(vB00) + wB01 * bfhi(vB01) + wB10 * bfhi(vB10) + wB11 * bfhi(vB11);
      int posA = jA / 9, tapA = jA % 9;
      int posB = jB / 9, tapB = jB % 9;
      *(u32*)&Alds[posA * 1162 + tapA * 128 + c] = pkt(loA, hiA);
      *(u32*)&Alds[posB * 1162 + tapB * 128 + c] = pkt(loB, hiB);
    }
  }
  __syncthreads();

  // ---- Phase 2: DCN MFMA (M=16, N=32/wave, K=1152) ----
  float4v acc[2];
  acc[0] = (float4v)(0.f); acc[1] = (float4v)(0.f);
  {
    const u16* ap = &Alds[nlo * 1162 + kgr * 8];
    const u16* b0p = &wTb[(((size_t)(wave * 2 + 0) * 36) * 64 + lane) * 8];
    const u16* b1p = &wTb[(((size_t)(wave * 2 + 1) * 36) * 64 + lane) * 8];
    for (int ks = 0; ks < 36; ++ks) {
      short8v a = *(const short8v*)(ap + ks * 32);
      short8v b0 = *(const short8v*)(b0p + (size_t)ks * 512);
      short8v b1 = *(const short8v*)(b1p + (size_t)ks * 512);
      acc[0] = __builtin_amdgcn_mfma_f32_16x16x32_bf16(a, b0, acc[0], 0, 0, 0);
      acc[1] = __builtin_amdgcn_mfma_f32_16x16x32_bf16(a, b1, acc[1], 0, 0, 0);
    }
  }
  __syncthreads();   // all waves done reading Alds before P overwrites it

  // ---- Phase 3: bn2 + relu -> P[pos][o] bf16 ----
  const int rbase = kgr * 4;
#pragma unroll
  for (int nt = 0; nt < 2; ++nt) {
    int o = (wave * 2 + nt) * 16 + nlo;
    float bd = b_dc[o], ss = s2[o], tt = t2[o];
#pragma unroll
    for (int r = 0; r < 4; ++r) {
      float v = acc[nt][r] + bd;
      v = fmaxf(ss * v + tt, 0.f);
      P[(rbase + r) * 136 + o] = bft(v);
    }
  }
  __syncthreads();

  // ---- Phase 4: conv3 MFMA (M=16, K=128) from P ----
  float4v acc2[2];
  acc2[0] = (float4v)(0.f); acc2[1] = (float4v)(0.f);
  {
    const u16* b0p = &w3b[(((size_t)(wave * 2 + 0) * 4) * 64 + lane) * 8];
    const u16* b1p = &w3b[(((size_t)(wave * 2 + 1) * 4) * 64 + lane) * 8];
#pragma unroll
    for (int ks = 0; ks < 4; ++ks) {
      short8v a = *(const short8v*)&P[nlo * 136 + ks * 32 + kgr * 8];
      short8v b0 = *(const short8v*)(b0p + ks * 512);
      short8v b1 = *(const short8v*)(b1p + ks * 512);
      acc2[0] = __builtin_amdgcn_mfma_f32_16x16x32_bf16(a, b0, acc2[0], 0, 0, 0);
      acc2[1] = __builtin_amdgcn_mfma_f32_16x16x32_bf16(a, b1, acc2[1], 0, 0, 0);
    }
  }

  // bn3 chain -> T2[o][pos] (disjoint from P region; no barrier needed)
#pragma unroll
  for (int nt = 0; nt < 2; ++nt) {
    int o = (wave * 2 + nt) * 16 + nlo;
    float sa = s3a[o], ta = t3a[o], sb = s3b[o], tb = t3b[o];
#pragma unroll
    for (int r = 0; r < 4; ++r) {
      float v = acc2[nt][r];
      v = fmaxf(sa * v + ta, 0.f);
      v = sb * v + tb;
      T2[o * 17 + rbase + r] = v;
    }
  }
  __syncthreads();

  // ---- Phase 5: transpose + ident + relu -> out NCHW fp32 ----
  {
    int o = tid >> 1, half = tid & 1;
    size_t g = ((size_t)((b * 128 + o) * 128 + h)) * 128 + wq * 16 + half * 8;
    const float* trow = &T2[o * 17 + half * 8];
    uint4 iv = *(const uint4*)&identb[g];
    u32 iw[4] = {iv.x, iv.y, iv.z, iv.w};
    float4 ov[2];
#pragma unroll
    for (int q = 0; q < 2; ++q) {
      float r0 = trow[q * 4 + 0] + bflo(iw[q * 2]);
      float r1 = trow[q * 4 + 1] + bfhi(iw[q * 2]);
      float r2 = trow[q * 4 + 2] + bflo(iw[q * 2 + 1]);
      float r3 = trow[q * 4 + 3] + bfhi(iw[q * 2 + 1]);
      ov[q] = make_float4(fmaxf(r0, 0.f), fmaxf(r1, 0.f), fmaxf(r2, 0.f), fmaxf(r3, 0.f));
    }
    *(float4*)&out[g] = ov[0];
    *(float4*)&out[g + 4] = ov[1];
  }
}

// ---------------------------------------------------------------------------
extern "C" void kernel_launch(void* const* d_in, const int* in_sizes, int n_in,
                              void* d_out, int out_size, void* d_ws, size_t ws_size,
                              hipStream_t stream) {
  const float* x     = (const float*)d_in[0];
  const float* w1    = (const float*)d_in[1];
  const float* s1a   = (const float*)d_in[2];
  const float* t1a   = (const float*)d_in[3];
  const float* s1b   = (const float*)d_in[4];
  const float* t1b   = (const float*)d_in[5];
  const float* w_off = (const float*)d_in[6];
  const float* b_off = (const float*)d_in[7];
  const float* w_dc  = (const float*)d_in[8];
  const float* b_dc  = (const float*)d_in[9];
  const float* s2    = (const float*)d_in[10];
  const float* t2    = (const float*)d_in[11];
  const float* w3    = (const float*)d_in[12];
  const float* s3a   = (const float*)d_in[13];
  const float* t3a   = (const float*)d_in[14];
  const float* s3b   = (const float*)d_in[15];
  const float* t3b   = (const float*)d_in[16];
  const float* w_ds  = (const float*)d_in[17];
  const float* b_ds  = (const float*)d_in[18];
  const float* sd    = (const float*)d_in[19];
  const float* td    = (const float*)d_in[20];

  char* ws = (char*)d_ws;
  u16* wTb    = (u16*)(ws + 0);            //    294,912 B
  u16* wB1    = (u16*)(ws + 294912);       //    131,072 B
  u16* w3b    = (u16*)(ws + 425984);       //     32,768 B
  u16* woffb  = (u16*)(ws + 458752);       //     73,728 B
  u16* out1   = (u16*)(ws + 532480);       // 16,777,216 B  NHWC bf16
  u16* identb = (u16*)(ws + 17309696);     // 16,777,216 B  NCHW bf16

  k_init  <<<1040, 256, 0, stream>>>(w_dc, w1, w_ds, w3, w_off, wTb, wB1, w3b, woffb);
  k_fused1<<<dim3(4, 128, 4), 256, 0, stream>>>(x, wB1, s1a, t1a, s1b, t1b, b_ds, sd, td, out1, identb);
  k_dcn   <<<dim3(8, 128, 4), 256, 0, stream>>>(out1, wTb, w3b, woffb, b_off, b_dc, s2, t2,
                                                s3a, t3a, s3b, t3b, identb, (float*)d_out);
}